// Round 3
// baseline (484.468 us; speedup 1.0000x reference)
//
#include <hip/hip_runtime.h>
#include <hip/hip_bf16.h>
#include <stdint.h>

typedef __attribute__((ext_vector_type(4))) float   f32x4;
typedef __attribute__((ext_vector_type(8))) __bf16  bf16x8;
typedef __attribute__((ext_vector_type(8))) short   s16x8;
typedef __attribute__((ext_vector_type(4))) unsigned short u16x4;
typedef __attribute__((ext_vector_type(4))) float   fl4;

#define DEVFN static __device__ __forceinline__

constexpr int BATCH = 2, SEQ = 2048, HID = 2048, NHEAD = 16, HDIM = 128;
constexpr int MROWS = BATCH * SEQ;   // 4096
constexpr int N3    = 3 * HID;       // 6144
constexpr float ATT_SCALE = 0.08838834764831845f;  // 1/sqrt(128)
constexpr float LOG2E = 1.44269504088896340736f;

DEVFN unsigned short f2bf(float f) {  // RNE float->bf16
  unsigned int u = __float_as_uint(f);
  u += 0x7FFFu + ((u >> 16) & 1u);
  return (unsigned short)(u >> 16);
}
DEVFN float bf2f(unsigned short h) { return __uint_as_float(((unsigned int)h) << 16); }

DEVFN void async_cp16(const void* g, void* l) {
  __builtin_amdgcn_global_load_lds(
      (__attribute__((address_space(1))) void*)g,
      (__attribute__((address_space(3))) void*)l, 16, 0, 0);
}

DEVFN f32x4 mfma_bf16(bf16x8 a, bf16x8 b, f32x4 c) {
  return __builtin_amdgcn_mfma_f32_16x16x32_bf16(a, b, c, 0, 0, 0);
}

// ---------------------------------------------------------------- split fp32 -> bf16 hi + lo
__global__ __launch_bounds__(256) void split_fp32(const float* __restrict__ x,
                                                  unsigned short* __restrict__ hi,
                                                  unsigned short* __restrict__ lo, int n4) {
  for (int i = blockIdx.x * blockDim.x + threadIdx.x; i < n4; i += gridDim.x * blockDim.x) {
    fl4 v = ((const fl4*)x)[i];
    u16x4 h, l;
#pragma unroll
    for (int j = 0; j < 4; j++) {
      unsigned short hb = f2bf(v[j]);
      h[j] = hb;
      l[j] = f2bf(v[j] - bf2f(hb));   // exact residual (same exponent range)
    }
    ((u16x4*)hi)[i] = h;
    ((u16x4*)lo)[i] = l;
  }
}

// ---------------------------------------------------------------- split + transpose W[R][C] -> T[C][R]
template <bool WRITE_LO>
__global__ __launch_bounds__(256) void split_transpose(const float* __restrict__ W,
                                                       unsigned short* __restrict__ Thi,
                                                       unsigned short* __restrict__ Tlo,
                                                       int R, int C) {
  __shared__ float tile[32][33];
  const int c0 = blockIdx.x * 32, r0 = blockIdx.y * 32;
  const int tx = threadIdx.x, ty = threadIdx.y;  // (32,8)
#pragma unroll
  for (int i = 0; i < 4; i++) tile[ty + 8 * i][tx] = W[(size_t)(r0 + ty + 8 * i) * C + c0 + tx];
  __syncthreads();
#pragma unroll
  for (int i = 0; i < 4; i++) {
    const float v = tile[tx][ty + 8 * i];
    const unsigned short hb = f2bf(v);
    const size_t o = (size_t)(c0 + ty + 8 * i) * R + r0 + tx;
    Thi[o] = hb;
    if constexpr (WRITE_LO) Tlo[o] = f2bf(v - bf2f(hb));
  }
}

// ---------------------------------------------------------------- GEMM: A[M][K] x Bt[N][K] (+bias) -> C[M][N]
// TERMS==3: split-bf16 (AhBh + AhBl + AlBh) ~ fp32 precision. TERMS==1: plain bf16.
template <int TERMS, bool OUT_BF16>
__global__ __launch_bounds__(256) void gemm_bt(const unsigned short* __restrict__ Ah,
                                               const unsigned short* __restrict__ Al,
                                               const unsigned short* __restrict__ Bh,
                                               const unsigned short* __restrict__ Bl,
                                               const float* __restrict__ bias,
                                               void* __restrict__ Cout, int Ndim, int Kdim) {
  constexpr int NBUF = (TERMS == 3) ? 4 : 2;
  __shared__ __align__(16) unsigned short smem[NBUF * 128 * 64];
  unsigned short* sAh = smem;
  unsigned short* sBh = smem + 128 * 64;
  unsigned short* sAl = (TERMS == 3) ? smem + 2 * 128 * 64 : smem;
  unsigned short* sBl = (TERMS == 3) ? smem + 3 * 128 * 64 : smem;

  const int tid = threadIdx.x;
  const int wid = tid >> 6, lane = tid & 63;
  const int wm = wid >> 1, wn = wid & 1;
  const int g = lane >> 4, q = lane & 15;
  const int n0 = blockIdx.x * 128, m0 = blockIdx.y * 128;
  const int lrow = lane >> 3, lcolB = (lane & 7) << 4;

  f32x4 acc[4][4] = {};

  for (int k0 = 0; k0 < Kdim; k0 += 64) {
    __syncthreads();
#pragma unroll
    for (int i = 0; i < 4; i++) {
      const int trow = (wid << 5) + (i << 3) + lrow;           // 0..127 tile row
      const int scol = lcolB ^ ((trow & 7) << 4);              // inverse-swizzled source col
      const int dstB = ((wid << 5) + (i << 3)) << 7;           // linear LDS dest (bytes)
      async_cp16((const char*)Ah + (((size_t)(m0 + trow) * Kdim + k0) << 1) + scol, (char*)sAh + dstB);
      async_cp16((const char*)Bh + (((size_t)(n0 + trow) * Kdim + k0) << 1) + scol, (char*)sBh + dstB);
      if (TERMS == 3) {
        async_cp16((const char*)Al + (((size_t)(m0 + trow) * Kdim + k0) << 1) + scol, (char*)sAl + dstB);
        async_cp16((const char*)Bl + (((size_t)(n0 + trow) * Kdim + k0) << 1) + scol, (char*)sBl + dstB);
      }
    }
    __syncthreads();
#pragma unroll
    for (int kk = 0; kk < 2; kk++) {
      const int kbyte = (kk << 6) + (g << 4);
      bf16x8 a_h[4], b_h[4], a_l[4], b_l[4];
#pragma unroll
      for (int mf = 0; mf < 4; mf++) {
        const int row = (wm << 6) + (mf << 4) + q;
        const int off = (row << 7) + (kbyte ^ ((row & 7) << 4));
        a_h[mf] = *(const bf16x8*)((const char*)sAh + off);
        if (TERMS == 3) a_l[mf] = *(const bf16x8*)((const char*)sAl + off);
      }
#pragma unroll
      for (int nf = 0; nf < 4; nf++) {
        const int row = (wn << 6) + (nf << 4) + q;
        const int off = (row << 7) + (kbyte ^ ((row & 7) << 4));
        b_h[nf] = *(const bf16x8*)((const char*)sBh + off);
        if (TERMS == 3) b_l[nf] = *(const bf16x8*)((const char*)sBl + off);
      }
#pragma unroll
      for (int mf = 0; mf < 4; mf++)
#pragma unroll
        for (int nf = 0; nf < 4; nf++) {
          acc[mf][nf] = mfma_bf16(a_h[mf], b_h[nf], acc[mf][nf]);
          if (TERMS == 3) {
            acc[mf][nf] = mfma_bf16(a_h[mf], b_l[nf], acc[mf][nf]);
            acc[mf][nf] = mfma_bf16(a_l[mf], b_h[nf], acc[mf][nf]);
          }
        }
    }
  }

  float bv[4];
#pragma unroll
  for (int nf = 0; nf < 4; nf++) bv[nf] = bias[n0 + (wn << 6) + (nf << 4) + q];
#pragma unroll
  for (int mf = 0; mf < 4; mf++) {
    const int rowg = m0 + (wm << 6) + (mf << 4) + (g << 2);
#pragma unroll
    for (int nf = 0; nf < 4; nf++) {
      const int colg = n0 + (wn << 6) + (nf << 4) + q;
#pragma unroll
      for (int r = 0; r < 4; r++) {
        const float v = acc[mf][nf][r] + bv[nf];
        if (OUT_BF16)
          ((unsigned short*)Cout)[(size_t)(rowg + r) * Ndim + colg] = f2bf(v);
        else
          ((float*)Cout)[(size_t)(rowg + r) * Ndim + colg] = v;
      }
    }
  }
}

// ---------------------------------------------------------------- V slice of QKV -> V^T [z][d][s]
__global__ __launch_bounds__(256) void transpose_v(const unsigned short* __restrict__ qkv,
                                                   unsigned short* __restrict__ vt) {
  __shared__ __align__(16) unsigned short tile[64][136];  // 272B row stride (16-mult)
  const int z = blockIdx.y, b = z >> 4, h = z & 15;
  const int s0 = blockIdx.x << 6;
  const int t = threadIdx.x;
  // Load FULL 64x128 tile: 1024 x s16x8 chunks -> 4 iterations of 256 threads.
#pragma unroll
  for (int i = 0; i < 4; i++) {
    const int idx = t + (i << 8);
    const int row = idx >> 4, ch = idx & 15;   // row 0..63, ch 0..15 (8 shorts each)
    *(s16x8*)&tile[row][ch << 3] =
        *(const s16x8*)(qkv + (size_t)(b * SEQ + s0 + row) * N3 + 2 * HID + h * HDIM + (ch << 3));
  }
  __syncthreads();
#pragma unroll
  for (int i = 0; i < 4; i++) {
    const int idx = t + (i << 8);
    const int d = idx >> 3, sc = idx & 7;
    s16x8 v;
#pragma unroll
    for (int j = 0; j < 8; j++) v[j] = (short)tile[(sc << 3) + j][d];
    *(s16x8*)(vt + (size_t)(z * HDIM + d) * SEQ + s0 + (sc << 3)) = v;
  }
}

// ---------------------------------------------------------------- flash attention (bf16 MFMA, fp32 softmax)
__global__ __launch_bounds__(256) void attn_kernel(const unsigned short* __restrict__ qkv,
                                                   const unsigned short* __restrict__ vt,
                                                   const float* __restrict__ mask,
                                                   unsigned short* __restrict__ ctx) {
  __shared__ __align__(16) unsigned short sK[64 * 128];   // [key][d], swizzled, 16KB
  __shared__ __align__(16) unsigned short sV[128 * 64];   // [d][key], swizzled, 16KB
  __shared__ __align__(16) unsigned short sP[4][16 * 72]; // per-wave P[q][key], 72-pad

  const int z = blockIdx.y, b = z >> 4, h = z & 15;
  const int qb = blockIdx.x;
  const int tid = threadIdx.x, wid = tid >> 6, lane = tid & 63;
  const int g = lane >> 4, q = lane & 15;
  const int q0 = (qb << 6) + (wid << 4);

  bf16x8 bq[4];  // Q as B-fragments: lane supplies Q[q][d = c*32 + g*8 + j]
  {
    const unsigned short* qrow = qkv + (size_t)(b * SEQ + q0 + q) * N3 + h * HDIM;
#pragma unroll
    for (int c = 0; c < 4; c++) bq[c] = *(const bf16x8*)(qrow + (c << 5) + (g << 3));
  }

  f32x4 acc[8] = {};
  float mrun = -1e30f, lrun = 0.f;
  const int lrow8 = lane >> 3, lcol8 = (lane & 7) << 4;
  const int lrow16 = lane >> 4, lcol16 = (lane & 15) << 4;
  unsigned short* myP = &sP[wid][0];

  for (int k0 = 0; k0 < SEQ; k0 += 64) {
    __syncthreads();
#pragma unroll
    for (int i = 0; i < 4; i++) {
      const int kr = (wid << 4) + (i << 2) + lrow16;  // key row 0..63 (256B rows)
      const int kcol = lcol16 ^ ((kr & 7) << 4);
      async_cp16((const char*)qkv + (((size_t)(b * SEQ + k0 + kr) * N3 + HID + h * HDIM) << 1) + kcol,
                 (char*)sK + (((wid << 4) + (i << 2)) << 8));
      const int vr = (wid << 5) + (i << 3) + lrow8;   // d row 0..127 (128B rows)
      const int vcol = lcol8 ^ ((vr & 7) << 4);
      async_cp16((const char*)vt + (((size_t)(z * HDIM + vr) * SEQ + k0) << 1) + vcol,
                 (char*)sV + (((wid << 5) + (i << 3)) << 7));
    }
    __syncthreads();

    // S^T = K * Q^T  (swapped): C col = q(lane&15), row = key = kt*16 + 4g + r
    f32x4 accs[4];
#pragma unroll
    for (int kt = 0; kt < 4; kt++) accs[kt] = (f32x4){0.f, 0.f, 0.f, 0.f};
#pragma unroll
    for (int c = 0; c < 4; c++) {
      const int kbyte = (c << 6) + (g << 4);
#pragma unroll
      for (int kt = 0; kt < 4; kt++) {
        const int key = (kt << 4) + q;
        const bf16x8 ak = *(const bf16x8*)((const char*)sK + (key << 8) + (kbyte ^ ((key & 7) << 4)));
        accs[kt] = mfma_bf16(ak, bq[c], accs[kt]);
      }
    }

    // online softmax (state per lane for q = lane&15, replicated over g-groups)
    float p[4][4];
    float mt = -1e30f;
#pragma unroll
    for (int kt = 0; kt < 4; kt++) {
      const fl4 mk = *(const fl4*)(mask + (size_t)b * SEQ + k0 + (kt << 4) + (g << 2));
#pragma unroll
      for (int r = 0; r < 4; r++) {
        const float s = accs[kt][r] * ATT_SCALE + mk[r];
        p[kt][r] = s;
        mt = fmaxf(mt, s);
      }
    }
    mt = fmaxf(mt, __shfl_xor(mt, 16));
    mt = fmaxf(mt, __shfl_xor(mt, 32));
    const float mnew = fmaxf(mrun, mt);
    const float fs = exp2f((mrun - mnew) * LOG2E);
    float ps = 0.f;
#pragma unroll
    for (int kt = 0; kt < 4; kt++)
#pragma unroll
      for (int r = 0; r < 4; r++) {
        const float e = exp2f((p[kt][r] - mnew) * LOG2E);
        p[kt][r] = e;
        ps += e;
      }
    ps += __shfl_xor(ps, 16);
    ps += __shfl_xor(ps, 32);
    lrun = lrun * fs + ps;
    mrun = mnew;

    // rescale ctx accumulator: acc rows are q-row = 4g + r -> fetch factor from lane (same grp)|4g+r
    const int sbase = (lane & 48) | (g << 2);
#pragma unroll
    for (int r = 0; r < 4; r++) {
      const float fr = __shfl(fs, sbase + r);
#pragma unroll
      for (int dt = 0; dt < 8; dt++) acc[dt][r] *= fr;
    }

    // P -> bf16 -> per-wave LDS [q][key]
#pragma unroll
    for (int kt = 0; kt < 4; kt++) {
      const unsigned int w0 = ((unsigned int)f2bf(p[kt][1]) << 16) | f2bf(p[kt][0]);
      const unsigned int w1 = ((unsigned int)f2bf(p[kt][3]) << 16) | f2bf(p[kt][2]);
      char* basep = (char*)myP + q * 144 + (((kt << 4) + (g << 2)) << 1);
      *(unsigned int*)basep = w0;
      *(unsigned int*)(basep + 4) = w1;
    }
    // HARD fence: the u32 P-stores and the bf16x8 P-loads below are different
    // access types (TBAA no-alias) -> without this, -O3 may hoist the ds_reads
    // above the ds_writes (tile 0 then reads uninit LDS -> inf/NaN). The
    // "memory" clobber is a compiler fence; lgkmcnt(0) guarantees HW completion.
    asm volatile("s_waitcnt lgkmcnt(0)" ::: "memory");
    __builtin_amdgcn_sched_barrier(0);

    // ctx += P * V : A-frag = P[q][k], B-frag = V^T rows (d) from sV
#pragma unroll
    for (int kc = 0; kc < 2; kc++) {
      const bf16x8 pa = *(const bf16x8*)((const char*)myP + q * 144 + (kc << 6) + (g << 4));
      const int kbyte = (kc << 6) + (g << 4);
#pragma unroll
      for (int dt = 0; dt < 8; dt++) {
        const int d = (dt << 4) + q;
        const bf16x8 bvv = *(const bf16x8*)((const char*)sV + (d << 7) + (kbyte ^ ((d & 7) << 4)));
        acc[dt] = mfma_bf16(pa, bvv, acc[dt]);
      }
    }
  }

  const int sbase = (lane & 48) | (g << 2);
#pragma unroll
  for (int r = 0; r < 4; r++) {
    const float lr = __shfl(lrun, sbase + r);
    const float inv = 1.f / lr;
    const int token = b * SEQ + (qb << 6) + (wid << 4) + (g << 2) + r;
    unsigned short* crow = ctx + (size_t)token * HID + h * HDIM + q;
#pragma unroll
    for (int dt = 0; dt < 8; dt++) crow[dt << 4] = f2bf(acc[dt][r] * inv);
  }
}

// ---------------------------------------------------------------- launch
extern "C" void kernel_launch(void* const* d_in, const int* in_sizes, int n_in,
                              void* d_out, int out_size, void* d_ws, size_t ws_size,
                              hipStream_t stream) {
  const float* hs   = (const float*)d_in[0];
  const float* mask = (const float*)d_in[1];
  const float* Wqkv = (const float*)d_in[2];
  const float* bqkv = (const float*)d_in[3];
  const float* Wout = (const float*)d_in[4];
  const float* bout = (const float*)d_in[5];

  char* ws = (char*)d_ws;
  size_t off = 0;
  auto alloc = [&](size_t n) { char* p = ws + off; off += (n + 255) & ~(size_t)255; return p; };
  unsigned short* hs_hi = (unsigned short*)alloc((size_t)MROWS * HID * 2);
  unsigned short* hs_lo = (unsigned short*)alloc((size_t)MROWS * HID * 2);
  unsigned short* wq_hi = (unsigned short*)alloc((size_t)N3 * HID * 2);
  unsigned short* wq_lo = (unsigned short*)alloc((size_t)N3 * HID * 2);
  unsigned short* wo_hi = (unsigned short*)alloc((size_t)HID * HID * 2);
  unsigned short* qkvb  = (unsigned short*)alloc((size_t)MROWS * N3 * 2);
  unsigned short* vtb   = (unsigned short*)alloc((size_t)BATCH * NHEAD * HDIM * SEQ * 2);
  unsigned short* ctxb  = (unsigned short*)alloc((size_t)MROWS * HID * 2);
  (void)ws_size;

  split_fp32<<<2048, 256, 0, stream>>>(hs, hs_hi, hs_lo, MROWS * HID / 4);
  dim3 tb(32, 8);
  split_transpose<true ><<<dim3(N3 / 32, HID / 32), tb, 0, stream>>>(Wqkv, wq_hi, wq_lo, HID, N3);
  split_transpose<false><<<dim3(HID / 32, HID / 32), tb, 0, stream>>>(Wout, wo_hi, nullptr, HID, HID);
  gemm_bt<3, true ><<<dim3(N3 / 128, MROWS / 128), 256, 0, stream>>>(hs_hi, hs_lo, wq_hi, wq_lo, bqkv, qkvb, N3, HID);
  transpose_v<<<dim3(SEQ / 64, BATCH * NHEAD), 256, 0, stream>>>(qkvb, vtb);
  attn_kernel<<<dim3(SEQ / 64, BATCH * NHEAD), 256, 0, stream>>>(qkvb, vtb, mask, ctxb);
  gemm_bt<1, false><<<dim3(HID / 128, MROWS / 128), 256, 0, stream>>>(ctxb, nullptr, wo_hi, nullptr, bout, (float*)d_out, HID, HID);
}

// Round 5
// 348.150 us; speedup vs baseline: 1.3916x; 1.3916x over previous
//
#include <hip/hip_runtime.h>
#include <hip/hip_bf16.h>
#include <stdint.h>

typedef __attribute__((ext_vector_type(4))) float   f32x4;
typedef __attribute__((ext_vector_type(8))) __bf16  bf16x8;
typedef __attribute__((ext_vector_type(8))) short   s16x8;
typedef __attribute__((ext_vector_type(4))) unsigned short u16x4;
typedef __attribute__((ext_vector_type(4))) float   fl4;

#define DEVFN static __device__ __forceinline__

constexpr int BATCH = 2, SEQ = 2048, HID = 2048, NHEAD = 16, HDIM = 128;
constexpr int MROWS = BATCH * SEQ;   // 4096
constexpr int N3    = 3 * HID;       // 6144
constexpr float ATT_SCALE = 0.08838834764831845f;  // 1/sqrt(128)
constexpr float LOG2E = 1.44269504088896340736f;

DEVFN unsigned short f2bf(float f) {  // RNE float->bf16
  unsigned int u = __float_as_uint(f);
  u += 0x7FFFu + ((u >> 16) & 1u);
  return (unsigned short)(u >> 16);
}
DEVFN float bf2f(unsigned short h) { return __uint_as_float(((unsigned int)h) << 16); }

DEVFN void async_cp16(const void* g, void* l) {
  __builtin_amdgcn_global_load_lds(
      (__attribute__((address_space(1))) void*)g,
      (__attribute__((address_space(3))) void*)l, 16, 0, 0);
}

DEVFN f32x4 mfma_bf16(bf16x8 a, bf16x8 b, f32x4 c) {
  return __builtin_amdgcn_mfma_f32_16x16x32_bf16(a, b, c, 0, 0, 0);
}

// ---------------------------------------------------------------- fp32 -> bf16 (RNE)
__global__ __launch_bounds__(256) void cvt_bf16(const float* __restrict__ x,
                                                unsigned short* __restrict__ hi, int n4) {
  for (int i = blockIdx.x * blockDim.x + threadIdx.x; i < n4; i += gridDim.x * blockDim.x) {
    fl4 v = ((const fl4*)x)[i];
    u16x4 h;
#pragma unroll
    for (int j = 0; j < 4; j++) h[j] = f2bf(v[j]);
    ((u16x4*)hi)[i] = h;
  }
}

// ---------------------------------------------------------------- transpose + cvt W[R][C] -> T[C][R] bf16
__global__ __launch_bounds__(256) void cvt_transpose(const float* __restrict__ W,
                                                     unsigned short* __restrict__ T,
                                                     int R, int C) {
  __shared__ float tile[32][33];
  const int c0 = blockIdx.x * 32, r0 = blockIdx.y * 32;
  const int tx = threadIdx.x, ty = threadIdx.y;  // (32,8)
#pragma unroll
  for (int i = 0; i < 4; i++) tile[ty + 8 * i][tx] = W[(size_t)(r0 + ty + 8 * i) * C + c0 + tx];
  __syncthreads();
#pragma unroll
  for (int i = 0; i < 4; i++) {
    const float v = tile[tx][ty + 8 * i];
    T[(size_t)(c0 + ty + 8 * i) * R + r0 + tx] = f2bf(v);
  }
}

// ---------------------------------------------------------------- GEMM: A[M][K] x Bt[N][K] (+bias) -> C[M][N]
// Plain bf16 MFMA, fp32 accumulate. 128x128 tile, BK=64, XOR-swizzled LDS.
template <bool OUT_BF16>
__global__ __launch_bounds__(256) void gemm_bt(const unsigned short* __restrict__ A,
                                               const unsigned short* __restrict__ Bt,
                                               const float* __restrict__ bias,
                                               void* __restrict__ Cout, int Ndim, int Kdim) {
  __shared__ __align__(16) unsigned short smem[2 * 128 * 64];
  unsigned short* sA = smem;
  unsigned short* sB = smem + 128 * 64;

  const int tid = threadIdx.x;
  const int wid = tid >> 6, lane = tid & 63;
  const int wm = wid >> 1, wn = wid & 1;
  const int g = lane >> 4, q = lane & 15;
  const int n0 = blockIdx.x * 128, m0 = blockIdx.y * 128;
  const int lrow = lane >> 3, lcolB = (lane & 7) << 4;

  f32x4 acc[4][4] = {};

  for (int k0 = 0; k0 < Kdim; k0 += 64) {
    __syncthreads();
#pragma unroll
    for (int i = 0; i < 4; i++) {
      const int trow = (wid << 5) + (i << 3) + lrow;           // 0..127 tile row
      const int scol = lcolB ^ ((trow & 7) << 4);              // inverse-swizzled source col
      const int dstB = ((wid << 5) + (i << 3)) << 7;           // linear LDS dest (bytes)
      async_cp16((const char*)A  + (((size_t)(m0 + trow) * Kdim + k0) << 1) + scol, (char*)sA + dstB);
      async_cp16((const char*)Bt + (((size_t)(n0 + trow) * Kdim + k0) << 1) + scol, (char*)sB + dstB);
    }
    __syncthreads();
#pragma unroll
    for (int kk = 0; kk < 2; kk++) {
      const int kbyte = (kk << 6) + (g << 4);
      bf16x8 a_h[4], b_h[4];
#pragma unroll
      for (int mf = 0; mf < 4; mf++) {
        const int row = (wm << 6) + (mf << 4) + q;
        a_h[mf] = *(const bf16x8*)((const char*)sA + (row << 7) + (kbyte ^ ((row & 7) << 4)));
      }
#pragma unroll
      for (int nf = 0; nf < 4; nf++) {
        const int row = (wn << 6) + (nf << 4) + q;
        b_h[nf] = *(const bf16x8*)((const char*)sB + (row << 7) + (kbyte ^ ((row & 7) << 4)));
      }
#pragma unroll
      for (int mf = 0; mf < 4; mf++)
#pragma unroll
        for (int nf = 0; nf < 4; nf++)
          acc[mf][nf] = mfma_bf16(a_h[mf], b_h[nf], acc[mf][nf]);
    }
  }

  float bv[4];
#pragma unroll
  for (int nf = 0; nf < 4; nf++) bv[nf] = bias[n0 + (wn << 6) + (nf << 4) + q];
#pragma unroll
  for (int mf = 0; mf < 4; mf++) {
    const int rowg = m0 + (wm << 6) + (mf << 4) + (g << 2);
#pragma unroll
    for (int nf = 0; nf < 4; nf++) {
      const int colg = n0 + (wn << 6) + (nf << 4) + q;
#pragma unroll
      for (int r = 0; r < 4; r++) {
        const float v = acc[mf][nf][r] + bv[nf];
        if (OUT_BF16)
          ((unsigned short*)Cout)[(size_t)(rowg + r) * Ndim + colg] = f2bf(v);
        else
          ((float*)Cout)[(size_t)(rowg + r) * Ndim + colg] = v;
      }
    }
  }
}

// ---------------------------------------------------------------- V slice of QKV -> V^T [z][d][s]
__global__ __launch_bounds__(256) void transpose_v(const unsigned short* __restrict__ qkv,
                                                   unsigned short* __restrict__ vt) {
  __shared__ __align__(16) unsigned short tile[64][136];  // 272B row stride (16-mult)
  const int z = blockIdx.y, b = z >> 4, h = z & 15;
  const int s0 = blockIdx.x << 6;
  const int t = threadIdx.x;
  // Load FULL 64x128 tile: 1024 x s16x8 chunks -> 4 iterations of 256 threads.
#pragma unroll
  for (int i = 0; i < 4; i++) {
    const int idx = t + (i << 8);
    const int row = idx >> 4, ch = idx & 15;   // row 0..63, ch 0..15 (8 shorts each)
    *(s16x8*)&tile[row][ch << 3] =
        *(const s16x8*)(qkv + (size_t)(b * SEQ + s0 + row) * N3 + 2 * HID + h * HDIM + (ch << 3));
  }
  __syncthreads();
#pragma unroll
  for (int i = 0; i < 4; i++) {
    const int idx = t + (i << 8);
    const int d = idx >> 3, sc = idx & 7;
    s16x8 v;
#pragma unroll
    for (int j = 0; j < 8; j++) v[j] = (short)tile[(sc << 3) + j][d];
    *(s16x8*)(vt + (size_t)(z * HDIM + d) * SEQ + s0 + (sc << 3)) = v;
  }
}

// ---------------------------------------------------------------- flash attention (bf16 MFMA, fp32 softmax)
__global__ __launch_bounds__(256) void attn_kernel(const unsigned short* __restrict__ qkv,
                                                   const unsigned short* __restrict__ vt,
                                                   const float* __restrict__ mask,
                                                   unsigned short* __restrict__ ctx) {
  __shared__ __align__(16) unsigned short sK[64 * 128];   // [key][d], swizzled, 16KB
  __shared__ __align__(16) unsigned short sV[128 * 64];   // [d][key], swizzled, 16KB
  __shared__ __align__(16) unsigned short sP[4][16 * 72]; // per-wave P[q][key], 72-pad

  const int z = blockIdx.y, b = z >> 4, h = z & 15;
  const int qb = blockIdx.x;
  const int tid = threadIdx.x, wid = tid >> 6, lane = tid & 63;
  const int g = lane >> 4, q = lane & 15;
  const int q0 = (qb << 6) + (wid << 4);

  bf16x8 bq[4];  // Q as B-fragments: lane supplies Q[q][d = c*32 + g*8 + j]
  {
    const unsigned short* qrow = qkv + (size_t)(b * SEQ + q0 + q) * N3 + h * HDIM;
#pragma unroll
    for (int c = 0; c < 4; c++) bq[c] = *(const bf16x8*)(qrow + (c << 5) + (g << 3));
  }

  f32x4 acc[8] = {};
  float mrun = -1e30f, lrun = 0.f;
  const int lrow8 = lane >> 3, lcol8 = (lane & 7) << 4;
  const int lrow16 = lane >> 4, lcol16 = (lane & 15) << 4;
  unsigned short* myP = &sP[wid][0];

  for (int k0 = 0; k0 < SEQ; k0 += 64) {
    __syncthreads();
#pragma unroll
    for (int i = 0; i < 4; i++) {
      const int kr = (wid << 4) + (i << 2) + lrow16;  // key row 0..63 (256B rows)
      const int kcol = lcol16 ^ ((kr & 7) << 4);
      async_cp16((const char*)qkv + (((size_t)(b * SEQ + k0 + kr) * N3 + HID + h * HDIM) << 1) + kcol,
                 (char*)sK + (((wid << 4) + (i << 2)) << 8));
      const int vr = (wid << 5) + (i << 3) + lrow8;   // d row 0..127 (128B rows)
      const int vcol = lcol8 ^ ((vr & 7) << 4);
      async_cp16((const char*)vt + (((size_t)(z * HDIM + vr) * SEQ + k0) << 1) + vcol,
                 (char*)sV + (((wid << 5) + (i << 3)) << 7));
    }
    __syncthreads();

    // S^T = K * Q^T  (swapped): C col = q(lane&15), row = key = kt*16 + 4g + r
    f32x4 accs[4];
#pragma unroll
    for (int kt = 0; kt < 4; kt++) accs[kt] = (f32x4){0.f, 0.f, 0.f, 0.f};
#pragma unroll
    for (int c = 0; c < 4; c++) {
      const int kbyte = (c << 6) + (g << 4);
#pragma unroll
      for (int kt = 0; kt < 4; kt++) {
        const int key = (kt << 4) + q;
        const bf16x8 ak = *(const bf16x8*)((const char*)sK + (key << 8) + (kbyte ^ ((key & 7) << 4)));
        accs[kt] = mfma_bf16(ak, bq[c], accs[kt]);
      }
    }

    // online softmax (state per lane for q = lane&15, replicated over g-groups)
    float p[4][4];
    float mt = -1e30f;
#pragma unroll
    for (int kt = 0; kt < 4; kt++) {
      const fl4 mk = *(const fl4*)(mask + (size_t)b * SEQ + k0 + (kt << 4) + (g << 2));
#pragma unroll
      for (int r = 0; r < 4; r++) {
        const float s = accs[kt][r] * ATT_SCALE + mk[r];
        p[kt][r] = s;
        mt = fmaxf(mt, s);
      }
    }
    mt = fmaxf(mt, __shfl_xor(mt, 16));
    mt = fmaxf(mt, __shfl_xor(mt, 32));
    const float mnew = fmaxf(mrun, mt);
    const float fs = exp2f((mrun - mnew) * LOG2E);
    float ps = 0.f;
#pragma unroll
    for (int kt = 0; kt < 4; kt++)
#pragma unroll
      for (int r = 0; r < 4; r++) {
        const float e = exp2f((p[kt][r] - mnew) * LOG2E);
        p[kt][r] = e;
        ps += e;
      }
    ps += __shfl_xor(ps, 16);
    ps += __shfl_xor(ps, 32);
    lrun = lrun * fs + ps;
    mrun = mnew;

    // rescale ctx accumulator: acc rows are q-row = 4g + r -> fetch factor from lane (same grp)|4g+r
    const int sbase = (lane & 48) | (g << 2);
#pragma unroll
    for (int r = 0; r < 4; r++) {
      const float fr = __shfl(fs, sbase + r);
#pragma unroll
      for (int dt = 0; dt < 8; dt++) acc[dt][r] *= fr;
    }

    // P -> bf16 -> per-wave LDS [q][key]
#pragma unroll
    for (int kt = 0; kt < 4; kt++) {
      const unsigned int w0 = ((unsigned int)f2bf(p[kt][1]) << 16) | f2bf(p[kt][0]);
      const unsigned int w1 = ((unsigned int)f2bf(p[kt][3]) << 16) | f2bf(p[kt][2]);
      char* basep = (char*)myP + q * 144 + (((kt << 4) + (g << 2)) << 1);
      *(unsigned int*)basep = w0;
      *(unsigned int*)(basep + 4) = w1;
    }
    // HARD fence: u32 P-stores vs bf16x8 P-loads are TBAA no-alias; prevent
    // hoisting of the ds_reads above the ds_writes and wait for HW completion.
    asm volatile("s_waitcnt lgkmcnt(0)" ::: "memory");
    __builtin_amdgcn_sched_barrier(0);

    // ctx += P * V : A-frag = P[q][k], B-frag = V^T rows (d) from sV
#pragma unroll
    for (int kc = 0; kc < 2; kc++) {
      const bf16x8 pa = *(const bf16x8*)((const char*)myP + q * 144 + (kc << 6) + (g << 4));
      const int kbyte = (kc << 6) + (g << 4);
#pragma unroll
      for (int dt = 0; dt < 8; dt++) {
        const int d = (dt << 4) + q;
        const bf16x8 bvv = *(const bf16x8*)((const char*)sV + (d << 7) + (kbyte ^ ((d & 7) << 4)));
        acc[dt] = mfma_bf16(pa, bvv, acc[dt]);
      }
    }
  }

  const int sbase = (lane & 48) | (g << 2);
#pragma unroll
  for (int r = 0; r < 4; r++) {
    const float lr = __shfl(lrun, sbase + r);
    const float inv = 1.f / lr;
    const int token = b * SEQ + (qb << 6) + (wid << 4) + (g << 2) + r;
    unsigned short* crow = ctx + (size_t)token * HID + h * HDIM + q;
#pragma unroll
    for (int dt = 0; dt < 8; dt++) crow[dt << 4] = f2bf(acc[dt][r] * inv);
  }
}

// ---------------------------------------------------------------- launch
extern "C" void kernel_launch(void* const* d_in, const int* in_sizes, int n_in,
                              void* d_out, int out_size, void* d_ws, size_t ws_size,
                              hipStream_t stream) {
  const float* hs   = (const float*)d_in[0];
  const float* mask = (const float*)d_in[1];
  const float* Wqkv = (const float*)d_in[2];
  const float* bqkv = (const float*)d_in[3];
  const float* Wout = (const float*)d_in[4];
  const float* bout = (const float*)d_in[5];

  char* ws = (char*)d_ws;
  size_t off = 0;
  auto alloc = [&](size_t n) { char* p = ws + off; off += (n + 255) & ~(size_t)255; return p; };
  unsigned short* hs_bf = (unsigned short*)alloc((size_t)MROWS * HID * 2);
  unsigned short* wq_bf = (unsigned short*)alloc((size_t)N3 * HID * 2);
  unsigned short* wo_bf = (unsigned short*)alloc((size_t)HID * HID * 2);
  unsigned short* qkvb  = (unsigned short*)alloc((size_t)MROWS * N3 * 2);
  unsigned short* vtb   = (unsigned short*)alloc((size_t)BATCH * NHEAD * HDIM * SEQ * 2);
  unsigned short* ctxb  = (unsigned short*)alloc((size_t)MROWS * HID * 2);
  (void)ws_size;

  cvt_bf16<<<2048, 256, 0, stream>>>(hs, hs_bf, MROWS * HID / 4);
  dim3 tb(32, 8);
  cvt_transpose<<<dim3(N3 / 32, HID / 32), tb, 0, stream>>>(Wqkv, wq_bf, HID, N3);
  cvt_transpose<<<dim3(HID / 32, HID / 32), tb, 0, stream>>>(Wout, wo_bf, HID, HID);
  gemm_bt<true ><<<dim3(N3 / 128, MROWS / 128), 256, 0, stream>>>(hs_bf, wq_bf, bqkv, qkvb, N3, HID);
  transpose_v<<<dim3(SEQ / 64, BATCH * NHEAD), 256, 0, stream>>>(qkvb, vtb);
  attn_kernel<<<dim3(SEQ / 64, BATCH * NHEAD), 256, 0, stream>>>(qkvb, vtb, mask, ctxb);
  gemm_bt<false><<<dim3(HID / 128, MROWS / 128), 256, 0, stream>>>(ctxb, wo_bf, bout, (float*)d_out, HID, HID);
}

// Round 6
// 305.241 us; speedup vs baseline: 1.5872x; 1.1406x over previous
//
#include <hip/hip_runtime.h>
#include <hip/hip_bf16.h>
#include <stdint.h>

typedef __attribute__((ext_vector_type(4))) float   f32x4;
typedef __attribute__((ext_vector_type(8))) __bf16  bf16x8;
typedef __attribute__((ext_vector_type(4))) __bf16  bf16x4;
typedef __attribute__((ext_vector_type(8))) short   s16x8;
typedef __attribute__((ext_vector_type(4))) unsigned short u16x4;
typedef __attribute__((ext_vector_type(4))) float   fl4;

#define DEVFN static __device__ __forceinline__

constexpr int BATCH = 2, SEQ = 2048, HID = 2048, NHEAD = 16, HDIM = 128;
constexpr int MROWS = BATCH * SEQ;   // 4096
constexpr int N3    = 3 * HID;       // 6144
constexpr float ATT_SCALE = 0.08838834764831845f;  // 1/sqrt(128)
constexpr float LOG2E = 1.44269504088896340736f;

DEVFN unsigned short f2bf(float f) {  // RNE float->bf16
  unsigned int u = __float_as_uint(f);
  u += 0x7FFFu + ((u >> 16) & 1u);
  return (unsigned short)(u >> 16);
}
DEVFN float bf2f(unsigned short h) { return __uint_as_float(((unsigned int)h) << 16); }

DEVFN void async_cp16(const void* g, void* l) {
  __builtin_amdgcn_global_load_lds(
      (__attribute__((address_space(1))) void*)g,
      (__attribute__((address_space(3))) void*)l, 16, 0, 0);
}

DEVFN f32x4 mfma_bf16(bf16x8 a, bf16x8 b, f32x4 c) {
  return __builtin_amdgcn_mfma_f32_16x16x32_bf16(a, b, c, 0, 0, 0);
}

// ---------------------------------------------------------------- fp32 -> bf16 (RNE)
__global__ __launch_bounds__(256) void cvt_bf16(const float* __restrict__ x,
                                                unsigned short* __restrict__ hi, int n4) {
  for (int i = blockIdx.x * blockDim.x + threadIdx.x; i < n4; i += gridDim.x * blockDim.x) {
    fl4 v = ((const fl4*)x)[i];
    u16x4 h;
#pragma unroll
    for (int j = 0; j < 4; j++) h[j] = f2bf(v[j]);
    ((u16x4*)hi)[i] = h;
  }
}

// ---------------------------------------------------------------- transpose + cvt W[R][C] -> T[C][R] bf16
__global__ __launch_bounds__(256) void cvt_transpose(const float* __restrict__ W,
                                                     unsigned short* __restrict__ T,
                                                     int R, int C) {
  __shared__ float tile[32][33];
  const int c0 = blockIdx.x * 32, r0 = blockIdx.y * 32;
  const int tx = threadIdx.x, ty = threadIdx.y;  // (32,8)
#pragma unroll
  for (int i = 0; i < 4; i++) tile[ty + 8 * i][tx] = W[(size_t)(r0 + ty + 8 * i) * C + c0 + tx];
  __syncthreads();
#pragma unroll
  for (int i = 0; i < 4; i++) {
    const float v = tile[tx][ty + 8 * i];
    T[(size_t)(c0 + ty + 8 * i) * R + r0 + tx] = f2bf(v);
  }
}

// ---------------------------------------------------------------- GEMM: A[M][K] x Bt[N][K] (+bias) -> C[M][N]
// Plain bf16 MFMA, fp32 accumulate. 128x128 tile, BK=64, XOR-swizzled LDS.
template <bool OUT_BF16>
__global__ __launch_bounds__(256) void gemm_bt(const unsigned short* __restrict__ A,
                                               const unsigned short* __restrict__ Bt,
                                               const float* __restrict__ bias,
                                               void* __restrict__ Cout, int Ndim, int Kdim) {
  __shared__ __align__(16) unsigned short smem[2 * 128 * 64];
  unsigned short* sA = smem;
  unsigned short* sB = smem + 128 * 64;

  const int tid = threadIdx.x;
  const int wid = tid >> 6, lane = tid & 63;
  const int wm = wid >> 1, wn = wid & 1;
  const int g = lane >> 4, q = lane & 15;
  const int n0 = blockIdx.x * 128, m0 = blockIdx.y * 128;
  const int lrow = lane >> 3, lcolB = (lane & 7) << 4;

  f32x4 acc[4][4] = {};

  for (int k0 = 0; k0 < Kdim; k0 += 64) {
    __syncthreads();
#pragma unroll
    for (int i = 0; i < 4; i++) {
      const int trow = (wid << 5) + (i << 3) + lrow;           // 0..127 tile row
      const int scol = lcolB ^ ((trow & 7) << 4);              // inverse-swizzled source col
      const int dstB = ((wid << 5) + (i << 3)) << 7;           // linear LDS dest (bytes)
      async_cp16((const char*)A  + (((size_t)(m0 + trow) * Kdim + k0) << 1) + scol, (char*)sA + dstB);
      async_cp16((const char*)Bt + (((size_t)(n0 + trow) * Kdim + k0) << 1) + scol, (char*)sB + dstB);
    }
    __syncthreads();
#pragma unroll
    for (int kk = 0; kk < 2; kk++) {
      const int kbyte = (kk << 6) + (g << 4);
      bf16x8 a_h[4], b_h[4];
#pragma unroll
      for (int mf = 0; mf < 4; mf++) {
        const int row = (wm << 6) + (mf << 4) + q;
        a_h[mf] = *(const bf16x8*)((const char*)sA + (row << 7) + (kbyte ^ ((row & 7) << 4)));
      }
#pragma unroll
      for (int nf = 0; nf < 4; nf++) {
        const int row = (wn << 6) + (nf << 4) + q;
        b_h[nf] = *(const bf16x8*)((const char*)sB + (row << 7) + (kbyte ^ ((row & 7) << 4)));
      }
#pragma unroll
      for (int mf = 0; mf < 4; mf++)
#pragma unroll
        for (int nf = 0; nf < 4; nf++)
          acc[mf][nf] = mfma_bf16(a_h[mf], b_h[nf], acc[mf][nf]);
    }
  }

  float bv[4];
#pragma unroll
  for (int nf = 0; nf < 4; nf++) bv[nf] = bias[n0 + (wn << 6) + (nf << 4) + q];
#pragma unroll
  for (int mf = 0; mf < 4; mf++) {
    const int rowg = m0 + (wm << 6) + (mf << 4) + (g << 2);
#pragma unroll
    for (int nf = 0; nf < 4; nf++) {
      const int colg = n0 + (wn << 6) + (nf << 4) + q;
#pragma unroll
      for (int r = 0; r < 4; r++) {
        const float v = acc[mf][nf][r] + bv[nf];
        if (OUT_BF16)
          ((unsigned short*)Cout)[(size_t)(rowg + r) * Ndim + colg] = f2bf(v);
        else
          ((float*)Cout)[(size_t)(rowg + r) * Ndim + colg] = v;
      }
    }
  }
}

// ---------------------------------------------------------------- V slice of QKV -> V^T [z][d][s]
__global__ __launch_bounds__(256) void transpose_v(const unsigned short* __restrict__ qkv,
                                                   unsigned short* __restrict__ vt) {
  __shared__ __align__(16) unsigned short tile[64][136];  // 272B row stride (16-mult)
  const int z = blockIdx.y, b = z >> 4, h = z & 15;
  const int s0 = blockIdx.x << 6;
  const int t = threadIdx.x;
  // Load FULL 64x128 tile: 1024 x s16x8 chunks -> 4 iterations of 256 threads.
#pragma unroll
  for (int i = 0; i < 4; i++) {
    const int idx = t + (i << 8);
    const int row = idx >> 4, ch = idx & 15;   // row 0..63, ch 0..15 (8 shorts each)
    *(s16x8*)&tile[row][ch << 3] =
        *(const s16x8*)(qkv + (size_t)(b * SEQ + s0 + row) * N3 + 2 * HID + h * HDIM + (ch << 3));
  }
  __syncthreads();
#pragma unroll
  for (int i = 0; i < 4; i++) {
    const int idx = t + (i << 8);
    const int d = idx >> 3, sc = idx & 7;
    s16x8 v;
#pragma unroll
    for (int j = 0; j < 8; j++) v[j] = (short)tile[(sc << 3) + j][d];
    *(s16x8*)(vt + (size_t)(z * HDIM + d) * SEQ + s0 + (sc << 3)) = v;
  }
}

// ---------------------------------------------------------------- flash attention (bf16 MFMA, fp32 softmax)
// 4 waves x 32 q-rows (2 q-sets of 16), KVBLK=64. Each K/V ds_read feeds 2 MFMAs.
__global__ __launch_bounds__(256, 2) void attn_kernel(const unsigned short* __restrict__ qkv,
                                                      const unsigned short* __restrict__ vt,
                                                      const float* __restrict__ mask,
                                                      unsigned short* __restrict__ ctx) {
  __shared__ __align__(16) unsigned short sK[64 * 128];    // [key][d], swizzled, 16KB
  __shared__ __align__(16) unsigned short sV[128 * 64];    // [d][key], swizzled, 16KB
  __shared__ __align__(16) unsigned short sP[4][32 * 72];  // per-wave P[32 q][64 k], 144B rows

  const int z = blockIdx.y, b = z >> 4, h = z & 15;
  const int qb = blockIdx.x;
  const int tid = threadIdx.x, wid = tid >> 6, lane = tid & 63;
  const int g = lane >> 4, q = lane & 15;
  const int q0 = (qb << 7) + (wid << 5);     // 128 q-rows/block, 32/wave

  bf16x8 bq[2][4];  // Q B-frags for 2 q-sets: lane supplies Q[q][d = c*32 + g*8 + j]
#pragma unroll
  for (int qs = 0; qs < 2; qs++) {
    const unsigned short* qrow = qkv + (size_t)(b * SEQ + q0 + (qs << 4) + q) * N3 + h * HDIM;
#pragma unroll
    for (int c = 0; c < 4; c++) bq[qs][c] = *(const bf16x8*)(qrow + (c << 5) + (g << 3));
  }

  f32x4 acc[2][8] = {};
  float mrun[2] = {-1e30f, -1e30f}, lrun[2] = {0.f, 0.f};
  const int lrow8 = lane >> 3, lcol8 = (lane & 7) << 4;
  const int lrow16 = lane >> 4, lcol16 = (lane & 15) << 4;
  unsigned short* myP = &sP[wid][0];
  const int sbase = (lane & 48) | (g << 2);

  for (int k0 = 0; k0 < SEQ; k0 += 64) {
    __syncthreads();
#pragma unroll
    for (int i = 0; i < 4; i++) {
      const int kr = (wid << 4) + (i << 2) + lrow16;  // key row 0..63 (256B rows)
      const int kcol = lcol16 ^ ((kr & 7) << 4);
      async_cp16((const char*)qkv + (((size_t)(b * SEQ + k0 + kr) * N3 + HID + h * HDIM) << 1) + kcol,
                 (char*)sK + (((wid << 4) + (i << 2)) << 8));
      const int vr = (wid << 5) + (i << 3) + lrow8;   // d row 0..127 (128B rows)
      const int vcol = lcol8 ^ ((vr & 7) << 4);
      async_cp16((const char*)vt + (((size_t)(z * HDIM + vr) * SEQ + k0) << 1) + vcol,
                 (char*)sV + (((wid << 5) + (i << 3)) << 7));
    }
    __syncthreads();

    // S^T = K * Q^T (swapped): C col = q, row = key = kt*16 + 4g + r. ak shared by both q-sets.
    f32x4 accs[2][4];
#pragma unroll
    for (int qs = 0; qs < 2; qs++)
#pragma unroll
      for (int kt = 0; kt < 4; kt++) accs[qs][kt] = (f32x4){0.f, 0.f, 0.f, 0.f};
#pragma unroll
    for (int c = 0; c < 4; c++) {
      const int kbyte = (c << 6) + (g << 4);
#pragma unroll
      for (int kt = 0; kt < 4; kt++) {
        const int key = (kt << 4) + q;
        const bf16x8 ak = *(const bf16x8*)((const char*)sK + (key << 8) + (kbyte ^ ((key & 7) << 4)));
        accs[0][kt] = mfma_bf16(ak, bq[0][c], accs[0][kt]);
        accs[1][kt] = mfma_bf16(ak, bq[1][c], accs[1][kt]);
      }
    }

    // online softmax per q-set (state per lane for q = lane&15, replicated over g)
#pragma unroll
    for (int qs = 0; qs < 2; qs++) {
      float sv[4][4];
      float mt = -1e30f;
#pragma unroll
      for (int kt = 0; kt < 4; kt++) {
        const fl4 mk = *(const fl4*)(mask + (size_t)b * SEQ + k0 + (kt << 4) + (g << 2));
#pragma unroll
        for (int r = 0; r < 4; r++) {
          const float s = accs[qs][kt][r] * ATT_SCALE + mk[r];
          sv[kt][r] = s;
          mt = fmaxf(mt, s);
        }
      }
      mt = fmaxf(mt, __shfl_xor(mt, 16));
      mt = fmaxf(mt, __shfl_xor(mt, 32));
      // defer-max (T13): skip O-rescale when max growth small; P bounded by e^8.
      if (!__all(mt <= mrun[qs] + 8.f)) {
        const float mnew = fmaxf(mrun[qs], mt);
        const float fs = exp2f((mrun[qs] - mnew) * LOG2E);
        lrun[qs] *= fs;
#pragma unroll
        for (int r = 0; r < 4; r++) {
          const float fr = __shfl(fs, sbase + r);
#pragma unroll
          for (int dt = 0; dt < 8; dt++) acc[qs][dt][r] *= fr;
        }
        mrun[qs] = mnew;
      }
      float ps = 0.f;
#pragma unroll
      for (int kt = 0; kt < 4; kt++) {
        bf16x4 pk;
#pragma unroll
        for (int r = 0; r < 4; r++) {
          const float e = exp2f((sv[kt][r] - mrun[qs]) * LOG2E);
          ps += e;
          pk[r] = (__bf16)e;   // native cvt (compiler emits v_cvt_pk_bf16_f32)
        }
        *(bf16x4*)((char*)myP + ((qs << 4) + q) * 144 + (((kt << 4) + (g << 2)) << 1)) = pk;
      }
      ps += __shfl_xor(ps, 16);
      ps += __shfl_xor(ps, 32);
      lrun[qs] += ps;
    }

    // HARD fence: bf16 P-stores vs bf16x8 P-loads ordering + HW completion (rule #18).
    asm volatile("s_waitcnt lgkmcnt(0)" ::: "memory");
    __builtin_amdgcn_sched_barrier(0);

    // ctx += P * V : A-frag = P[q][k], B-frag = V^T rows (d) from sV. bvv shared by both q-sets.
#pragma unroll
    for (int kc = 0; kc < 2; kc++) {
      const bf16x8 pa0 = *(const bf16x8*)((const char*)myP + q * 144 + (kc << 6) + (g << 4));
      const bf16x8 pa1 = *(const bf16x8*)((const char*)myP + (16 + q) * 144 + (kc << 6) + (g << 4));
      const int kbyte = (kc << 6) + (g << 4);
#pragma unroll
      for (int dt = 0; dt < 8; dt++) {
        const int d = (dt << 4) + q;
        const bf16x8 bvv = *(const bf16x8*)((const char*)sV + (d << 7) + (kbyte ^ ((d & 7) << 4)));
        acc[0][dt] = mfma_bf16(pa0, bvv, acc[0][dt]);
        acc[1][dt] = mfma_bf16(pa1, bvv, acc[1][dt]);
      }
    }
  }

#pragma unroll
  for (int qs = 0; qs < 2; qs++)
#pragma unroll
    for (int r = 0; r < 4; r++) {
      const float lr = __shfl(lrun[qs], sbase + r);
      const float inv = 1.f / lr;
      const int token = b * SEQ + (qb << 7) + (wid << 5) + (qs << 4) + (g << 2) + r;
      unsigned short* crow = ctx + (size_t)token * HID + h * HDIM + q;
#pragma unroll
      for (int dt = 0; dt < 8; dt++) crow[dt << 4] = f2bf(acc[qs][dt][r] * inv);
    }
}

// ---------------------------------------------------------------- launch
extern "C" void kernel_launch(void* const* d_in, const int* in_sizes, int n_in,
                              void* d_out, int out_size, void* d_ws, size_t ws_size,
                              hipStream_t stream) {
  const float* hs   = (const float*)d_in[0];
  const float* mask = (const float*)d_in[1];
  const float* Wqkv = (const float*)d_in[2];
  const float* bqkv = (const float*)d_in[3];
  const float* Wout = (const float*)d_in[4];
  const float* bout = (const float*)d_in[5];

  char* ws = (char*)d_ws;
  size_t off = 0;
  auto alloc = [&](size_t n) { char* p = ws + off; off += (n + 255) & ~(size_t)255; return p; };
  unsigned short* hs_bf = (unsigned short*)alloc((size_t)MROWS * HID * 2);
  unsigned short* wq_bf = (unsigned short*)alloc((size_t)N3 * HID * 2);
  unsigned short* wo_bf = (unsigned short*)alloc((size_t)HID * HID * 2);
  unsigned short* qkvb  = (unsigned short*)alloc((size_t)MROWS * N3 * 2);
  unsigned short* vtb   = (unsigned short*)alloc((size_t)BATCH * NHEAD * HDIM * SEQ * 2);
  unsigned short* ctxb  = (unsigned short*)alloc((size_t)MROWS * HID * 2);
  (void)ws_size;

  cvt_bf16<<<2048, 256, 0, stream>>>(hs, hs_bf, MROWS * HID / 4);
  dim3 tb(32, 8);
  cvt_transpose<<<dim3(N3 / 32, HID / 32), tb, 0, stream>>>(Wqkv, wq_bf, HID, N3);
  cvt_transpose<<<dim3(HID / 32, HID / 32), tb, 0, stream>>>(Wout, wo_bf, HID, HID);
  gemm_bt<true ><<<dim3(N3 / 128, MROWS / 128), 256, 0, stream>>>(hs_bf, wq_bf, bqkv, qkvb, N3, HID);
  transpose_v<<<dim3(SEQ / 64, BATCH * NHEAD), 256, 0, stream>>>(qkvb, vtb);
  attn_kernel<<<dim3(SEQ / 128, BATCH * NHEAD), 256, 0, stream>>>(qkvb, vtb, mask, ctxb);
  gemm_bt<false><<<dim3(HID / 128, MROWS / 128), 256, 0, stream>>>(ctxb, wo_bf, bout, (float*)d_out, HID, HID);
}

// Round 7
// 278.014 us; speedup vs baseline: 1.7426x; 1.0979x over previous
//
#include <hip/hip_runtime.h>
#include <hip/hip_bf16.h>
#include <stdint.h>

typedef __attribute__((ext_vector_type(4))) float   f32x4;
typedef __attribute__((ext_vector_type(8))) __bf16  bf16x8;
typedef __attribute__((ext_vector_type(4))) __bf16  bf16x4;
typedef __attribute__((ext_vector_type(8))) short   s16x8;
typedef __attribute__((ext_vector_type(4))) unsigned short u16x4;
typedef __attribute__((ext_vector_type(4))) float   fl4;

#define DEVFN static __device__ __forceinline__

constexpr int BATCH = 2, SEQ = 2048, HID = 2048, NHEAD = 16, HDIM = 128;
constexpr int MROWS = BATCH * SEQ;   // 4096
constexpr int N3    = 3 * HID;       // 6144
constexpr float ATT_SCALE = 0.08838834764831845f;  // 1/sqrt(128)
constexpr float LOG2E = 1.44269504088896340736f;

DEVFN unsigned short f2bf(float f) {  // RNE float->bf16
  unsigned int u = __float_as_uint(f);
  u += 0x7FFFu + ((u >> 16) & 1u);
  return (unsigned short)(u >> 16);
}
DEVFN float bf2f(unsigned short h) { return __uint_as_float(((unsigned int)h) << 16); }

DEVFN void async_cp16(const void* g, void* l) {
  __builtin_amdgcn_global_load_lds(
      (__attribute__((address_space(1))) void*)g,
      (__attribute__((address_space(3))) void*)l, 16, 0, 0);
}

DEVFN f32x4 mfma_bf16(bf16x8 a, bf16x8 b, f32x4 c) {
  return __builtin_amdgcn_mfma_f32_16x16x32_bf16(a, b, c, 0, 0, 0);
}

// ---------------------------------------------------------------- fp32 -> bf16 (RNE)
__global__ __launch_bounds__(256) void cvt_bf16(const float* __restrict__ x,
                                                unsigned short* __restrict__ hi, int n4) {
  for (int i = blockIdx.x * blockDim.x + threadIdx.x; i < n4; i += gridDim.x * blockDim.x) {
    fl4 v = ((const fl4*)x)[i];
    u16x4 h;
#pragma unroll
    for (int j = 0; j < 4; j++) h[j] = f2bf(v[j]);
    ((u16x4*)hi)[i] = h;
  }
}

// ---------------------------------------------------------------- transpose + cvt W[R][C] -> T[C][R] bf16
__global__ __launch_bounds__(256) void cvt_transpose(const float* __restrict__ W,
                                                     unsigned short* __restrict__ T,
                                                     int R, int C) {
  __shared__ float tile[32][33];
  const int c0 = blockIdx.x * 32, r0 = blockIdx.y * 32;
  const int tx = threadIdx.x, ty = threadIdx.y;  // (32,8)
#pragma unroll
  for (int i = 0; i < 4; i++) tile[ty + 8 * i][tx] = W[(size_t)(r0 + ty + 8 * i) * C + c0 + tx];
  __syncthreads();
#pragma unroll
  for (int i = 0; i < 4; i++) {
    const float v = tile[tx][ty + 8 * i];
    T[(size_t)(c0 + ty + 8 * i) * R + r0 + tx] = f2bf(v);
  }
}

// ---------------------------------------------------------------- ring-pipelined GEMM
// C[M][N] = A[M][2048] x Bt[N][2048]^T + bias. BM=256, BN=128, BK=64.
// 512 thr (8 waves, 2M x 4N), per-wave out 128x64 (M_rep=8, N_rep=2).
// 3-slot LDS ring (144 KB), prefetch distance 2, ONE raw s_barrier + ONE
// counted vmcnt(6) per K-tile (T3/T4: loads stay in flight across barriers).
// Safety: iter t reads slot t%3 only; stage issued after barrier@t targets
// (t+2)%3 != t%3, whose last readers (iter t-1) all passed barrier@t.
template <bool OUT_BF16>
__global__ __launch_bounds__(512, 1) void gemm_ring(const unsigned short* __restrict__ A,
                                                    const unsigned short* __restrict__ Bt,
                                                    const float* __restrict__ bias,
                                                    void* __restrict__ Cout, int Ndim) {
  constexpr int KDIM  = 2048;
  constexpr int NT    = KDIM / 64;        // 32 K-tiles
  constexpr int ASLOT = 256 * 64;         // shorts per A tile
  constexpr int BSLOT = 128 * 64;
  constexpr int SLOT  = ASLOT + BSLOT;    // 24576 shorts = 48 KB
  __shared__ __align__(16) unsigned short smem[3 * SLOT];  // 144 KB

  const int tid = threadIdx.x;
  const int wid = tid >> 6, lane = tid & 63;
  const int wm = wid >> 2, wn = wid & 3;   // 2 x 4 wave grid
  const int g = lane >> 4, q = lane & 15;
  const int n0 = blockIdx.x * 128, m0 = blockIdx.y * 256;

  // staging: per round 8 waves x 8 rows x 128B; pre-swizzled global source col
  const int srow = (wid << 3) + (lane >> 3);                  // 0..63
  const int scol = (((lane & 7) ^ (lane >> 3)) << 4);         // inverse-swizzle
  const char* gA = (const char*)A  + ((size_t)(m0 + srow) * KDIM) * 2 + scol;
  const char* gB = (const char*)Bt + ((size_t)(n0 + srow) * KDIM) * 2 + scol;
  const int dbase = ((wid << 3)) << 7;                        // wave-uniform LDS byte base

  f32x4 acc[8][2] = {};
  const int axor = (q & 7) << 4;

  auto STAGE = [&](int tt, int slot) {
    char* sA = (char*)(smem + slot * SLOT);
    char* sB = (char*)(smem + slot * SLOT + ASLOT);
    const size_t koff = (size_t)tt << 7;  // tt*128 bytes
#pragma unroll
    for (int i = 0; i < 4; i++)
      async_cp16(gA + (size_t)(i * 64) * (KDIM * 2) + koff, sA + dbase + (i << 13));
#pragma unroll
    for (int i = 0; i < 2; i++)
      async_cp16(gB + (size_t)(i * 64) * (KDIM * 2) + koff, sB + dbase + (i << 13));
  };

  auto COMPUTE = [&](int slot) {
    const char* sA = (const char*)(smem + slot * SLOT);
    const char* sB = (const char*)(smem + slot * SLOT + ASLOT);
#pragma unroll
    for (int ks = 0; ks < 2; ks++) {
      const int kb = (ks << 6) + (g << 4);
      bf16x8 av[8], bv[2];
#pragma unroll
      for (int nf = 0; nf < 2; nf++) {
        const int row = (wn << 5) + (nf << 4) + q;
        bv[nf] = *(const bf16x8*)(sB + (row << 7) + (kb ^ axor));
      }
#pragma unroll
      for (int mf = 0; mf < 8; mf++) {
        const int row = (wm << 7) + (mf << 4) + q;
        av[mf] = *(const bf16x8*)(sA + (row << 7) + (kb ^ axor));
      }
#pragma unroll
      for (int mf = 0; mf < 8; mf++)
#pragma unroll
        for (int nf = 0; nf < 2; nf++)
          acc[mf][nf] = mfma_bf16(av[mf], bv[nf], acc[mf][nf]);
    }
  };

  STAGE(0, 0);
  STAGE(1, 1);
  int s2 = 2, sc = 0;
#pragma unroll 1
  for (int t = 0; t < NT - 2; ++t) {
    asm volatile("s_waitcnt vmcnt(6)" ::: "memory");   // my tile-t loads done (t+1 may fly)
    __builtin_amdgcn_s_barrier();                      // => ALL threads' tile-t loads landed
    asm volatile("" ::: "memory");
    STAGE(t + 2, s2);
    COMPUTE(sc);
    s2 = (s2 == 2) ? 0 : s2 + 1;
    sc = (sc == 2) ? 0 : sc + 1;
  }
  asm volatile("s_waitcnt vmcnt(6)" ::: "memory");
  __builtin_amdgcn_s_barrier();
  asm volatile("" ::: "memory");
  COMPUTE(sc);
  sc = (sc == 2) ? 0 : sc + 1;
  asm volatile("s_waitcnt vmcnt(0)" ::: "memory");
  __builtin_amdgcn_s_barrier();
  asm volatile("" ::: "memory");
  COMPUTE(sc);

  float bvv[2];
#pragma unroll
  for (int nf = 0; nf < 2; nf++) bvv[nf] = bias[n0 + (wn << 5) + (nf << 4) + q];
#pragma unroll
  for (int mf = 0; mf < 8; mf++) {
    const int rowg = m0 + (wm << 7) + (mf << 4) + (g << 2);
#pragma unroll
    for (int nf = 0; nf < 2; nf++) {
      const int colg = n0 + (wn << 5) + (nf << 4) + q;
#pragma unroll
      for (int r = 0; r < 4; r++) {
        const float v = acc[mf][nf][r] + bvv[nf];
        if (OUT_BF16)
          ((unsigned short*)Cout)[(size_t)(rowg + r) * Ndim + colg] = f2bf(v);
        else
          ((float*)Cout)[(size_t)(rowg + r) * Ndim + colg] = v;
      }
    }
  }
}

// ---------------------------------------------------------------- V slice of QKV -> V^T [z][d][s]
__global__ __launch_bounds__(256) void transpose_v(const unsigned short* __restrict__ qkv,
                                                   unsigned short* __restrict__ vt) {
  __shared__ __align__(16) unsigned short tile[64][136];  // 272B row stride (16-mult)
  const int z = blockIdx.y, b = z >> 4, h = z & 15;
  const int s0 = blockIdx.x << 6;
  const int t = threadIdx.x;
#pragma unroll
  for (int i = 0; i < 4; i++) {
    const int idx = t + (i << 8);
    const int row = idx >> 4, ch = idx & 15;   // row 0..63, ch 0..15 (8 shorts each)
    *(s16x8*)&tile[row][ch << 3] =
        *(const s16x8*)(qkv + (size_t)(b * SEQ + s0 + row) * N3 + 2 * HID + h * HDIM + (ch << 3));
  }
  __syncthreads();
#pragma unroll
  for (int i = 0; i < 4; i++) {
    const int idx = t + (i << 8);
    const int d = idx >> 3, sc = idx & 7;
    s16x8 v;
#pragma unroll
    for (int j = 0; j < 8; j++) v[j] = (short)tile[(sc << 3) + j][d];
    *(s16x8*)(vt + (size_t)(z * HDIM + d) * SEQ + s0 + (sc << 3)) = v;
  }
}

// ---------------------------------------------------------------- flash attention (bf16 MFMA, fp32 softmax)
// 4 waves x 32 q-rows (2 q-sets of 16), KVBLK=64. Each K/V ds_read feeds 2 MFMAs.
__global__ __launch_bounds__(256, 2) void attn_kernel(const unsigned short* __restrict__ qkv,
                                                      const unsigned short* __restrict__ vt,
                                                      const float* __restrict__ mask,
                                                      unsigned short* __restrict__ ctx) {
  __shared__ __align__(16) unsigned short sK[64 * 128];    // [key][d], swizzled, 16KB
  __shared__ __align__(16) unsigned short sV[128 * 64];    // [d][key], swizzled, 16KB
  __shared__ __align__(16) unsigned short sP[4][32 * 72];  // per-wave P[32 q][64 k], 144B rows

  const int z = blockIdx.y, b = z >> 4, h = z & 15;
  const int qb = blockIdx.x;
  const int tid = threadIdx.x, wid = tid >> 6, lane = tid & 63;
  const int g = lane >> 4, q = lane & 15;
  const int q0 = (qb << 7) + (wid << 5);     // 128 q-rows/block, 32/wave

  bf16x8 bq[2][4];  // Q B-frags for 2 q-sets: lane supplies Q[q][d = c*32 + g*8 + j]
#pragma unroll
  for (int qs = 0; qs < 2; qs++) {
    const unsigned short* qrow = qkv + (size_t)(b * SEQ + q0 + (qs << 4) + q) * N3 + h * HDIM;
#pragma unroll
    for (int c = 0; c < 4; c++) bq[qs][c] = *(const bf16x8*)(qrow + (c << 5) + (g << 3));
  }

  f32x4 acc[2][8] = {};
  float mrun[2] = {-1e30f, -1e30f}, lrun[2] = {0.f, 0.f};
  const int lrow8 = lane >> 3, lcol8 = (lane & 7) << 4;
  const int lrow16 = lane >> 4, lcol16 = (lane & 15) << 4;
  unsigned short* myP = &sP[wid][0];
  const int sbase = (lane & 48) | (g << 2);

  for (int k0 = 0; k0 < SEQ; k0 += 64) {
    __syncthreads();
#pragma unroll
    for (int i = 0; i < 4; i++) {
      const int kr = (wid << 4) + (i << 2) + lrow16;  // key row 0..63 (256B rows)
      const int kcol = lcol16 ^ ((kr & 7) << 4);
      async_cp16((const char*)qkv + (((size_t)(b * SEQ + k0 + kr) * N3 + HID + h * HDIM) << 1) + kcol,
                 (char*)sK + (((wid << 4) + (i << 2)) << 8));
      const int vr = (wid << 5) + (i << 3) + lrow8;   // d row 0..127 (128B rows)
      const int vcol = lcol8 ^ ((vr & 7) << 4);
      async_cp16((const char*)vt + (((size_t)(z * HDIM + vr) * SEQ + k0) << 1) + vcol,
                 (char*)sV + (((wid << 5) + (i << 3)) << 7));
    }
    __syncthreads();

    // S^T = K * Q^T (swapped): C col = q, row = key = kt*16 + 4g + r. ak shared by both q-sets.
    f32x4 accs[2][4];
#pragma unroll
    for (int qs = 0; qs < 2; qs++)
#pragma unroll
      for (int kt = 0; kt < 4; kt++) accs[qs][kt] = (f32x4){0.f, 0.f, 0.f, 0.f};
#pragma unroll
    for (int c = 0; c < 4; c++) {
      const int kbyte = (c << 6) + (g << 4);
#pragma unroll
      for (int kt = 0; kt < 4; kt++) {
        const int key = (kt << 4) + q;
        const bf16x8 ak = *(const bf16x8*)((const char*)sK + (key << 8) + (kbyte ^ ((key & 7) << 4)));
        accs[0][kt] = mfma_bf16(ak, bq[0][c], accs[0][kt]);
        accs[1][kt] = mfma_bf16(ak, bq[1][c], accs[1][kt]);
      }
    }

    // online softmax per q-set (state per lane for q = lane&15, replicated over g)
#pragma unroll
    for (int qs = 0; qs < 2; qs++) {
      float sv[4][4];
      float mt = -1e30f;
#pragma unroll
      for (int kt = 0; kt < 4; kt++) {
        const fl4 mk = *(const fl4*)(mask + (size_t)b * SEQ + k0 + (kt << 4) + (g << 2));
#pragma unroll
        for (int r = 0; r < 4; r++) {
          const float s = accs[qs][kt][r] * ATT_SCALE + mk[r];
          sv[kt][r] = s;
          mt = fmaxf(mt, s);
        }
      }
      mt = fmaxf(mt, __shfl_xor(mt, 16));
      mt = fmaxf(mt, __shfl_xor(mt, 32));
      // defer-max (T13): skip O-rescale when max growth small; P bounded by e^8.
      if (!__all(mt <= mrun[qs] + 8.f)) {
        const float mnew = fmaxf(mrun[qs], mt);
        const float fs = exp2f((mrun[qs] - mnew) * LOG2E);
        lrun[qs] *= fs;
#pragma unroll
        for (int r = 0; r < 4; r++) {
          const float fr = __shfl(fs, sbase + r);
#pragma unroll
          for (int dt = 0; dt < 8; dt++) acc[qs][dt][r] *= fr;
        }
        mrun[qs] = mnew;
      }
      float ps = 0.f;
#pragma unroll
      for (int kt = 0; kt < 4; kt++) {
        bf16x4 pk;
#pragma unroll
        for (int r = 0; r < 4; r++) {
          const float e = exp2f((sv[kt][r] - mrun[qs]) * LOG2E);
          ps += e;
          pk[r] = (__bf16)e;   // native cvt (compiler emits v_cvt_pk_bf16_f32)
        }
        *(bf16x4*)((char*)myP + ((qs << 4) + q) * 144 + (((kt << 4) + (g << 2)) << 1)) = pk;
      }
      ps += __shfl_xor(ps, 16);
      ps += __shfl_xor(ps, 32);
      lrun[qs] += ps;
    }

    // HARD fence: bf16 P-stores vs bf16x8 P-loads ordering + HW completion (rule #18).
    asm volatile("s_waitcnt lgkmcnt(0)" ::: "memory");
    __builtin_amdgcn_sched_barrier(0);

    // ctx += P * V : A-frag = P[q][k], B-frag = V^T rows (d) from sV. bvv shared by both q-sets.
#pragma unroll
    for (int kc = 0; kc < 2; kc++) {
      const bf16x8 pa0 = *(const bf16x8*)((const char*)myP + q * 144 + (kc << 6) + (g << 4));
      const bf16x8 pa1 = *(const bf16x8*)((const char*)myP + (16 + q) * 144 + (kc << 6) + (g << 4));
      const int kbyte = (kc << 6) + (g << 4);
#pragma unroll
      for (int dt = 0; dt < 8; dt++) {
        const int d = (dt << 4) + q;
        const bf16x8 bvv = *(const bf16x8*)((const char*)sV + (d << 7) + (kbyte ^ ((d & 7) << 4)));
        acc[0][dt] = mfma_bf16(pa0, bvv, acc[0][dt]);
        acc[1][dt] = mfma_bf16(pa1, bvv, acc[1][dt]);
      }
    }
  }

#pragma unroll
  for (int qs = 0; qs < 2; qs++)
#pragma unroll
    for (int r = 0; r < 4; r++) {
      const float lr = __shfl(lrun[qs], sbase + r);
      const float inv = 1.f / lr;
      const int token = b * SEQ + (qb << 7) + (wid << 5) + (qs << 4) + (g << 2) + r;
      unsigned short* crow = ctx + (size_t)token * HID + h * HDIM + q;
#pragma unroll
      for (int dt = 0; dt < 8; dt++) crow[dt << 4] = f2bf(acc[qs][dt][r] * inv);
    }
}

// ---------------------------------------------------------------- launch
extern "C" void kernel_launch(void* const* d_in, const int* in_sizes, int n_in,
                              void* d_out, int out_size, void* d_ws, size_t ws_size,
                              hipStream_t stream) {
  const float* hs   = (const float*)d_in[0];
  const float* mask = (const float*)d_in[1];
  const float* Wqkv = (const float*)d_in[2];
  const float* bqkv = (const float*)d_in[3];
  const float* Wout = (const float*)d_in[4];
  const float* bout = (const float*)d_in[5];

  char* ws = (char*)d_ws;
  size_t off = 0;
  auto alloc = [&](size_t n) { char* p = ws + off; off += (n + 255) & ~(size_t)255; return p; };
  unsigned short* hs_bf = (unsigned short*)alloc((size_t)MROWS * HID * 2);
  unsigned short* wq_bf = (unsigned short*)alloc((size_t)N3 * HID * 2);
  unsigned short* wo_bf = (unsigned short*)alloc((size_t)HID * HID * 2);
  unsigned short* qkvb  = (unsigned short*)alloc((size_t)MROWS * N3 * 2);
  unsigned short* vtb   = (unsigned short*)alloc((size_t)BATCH * NHEAD * HDIM * SEQ * 2);
  unsigned short* ctxb  = (unsigned short*)alloc((size_t)MROWS * HID * 2);
  (void)ws_size;

  cvt_bf16<<<2048, 256, 0, stream>>>(hs, hs_bf, MROWS * HID / 4);
  dim3 tb(32, 8);
  cvt_transpose<<<dim3(N3 / 32, HID / 32), tb, 0, stream>>>(Wqkv, wq_bf, HID, N3);
  cvt_transpose<<<dim3(HID / 32, HID / 32), tb, 0, stream>>>(Wout, wo_bf, HID, HID);
  gemm_ring<true ><<<dim3(N3 / 128, MROWS / 256), 512, 0, stream>>>(hs_bf, wq_bf, bqkv, qkvb, N3);
  transpose_v<<<dim3(SEQ / 64, BATCH * NHEAD), 256, 0, stream>>>(qkvb, vtb);
  attn_kernel<<<dim3(SEQ / 128, BATCH * NHEAD), 256, 0, stream>>>(qkvb, vtb, mask, ctxb);
  gemm_ring<false><<<dim3(HID / 128, MROWS / 256), 512, 0, stream>>>(ctxb, wo_bf, bout, (float*)d_out, HID);
}

// Round 8
// 277.477 us; speedup vs baseline: 1.7460x; 1.0019x over previous
//
#include <hip/hip_runtime.h>
#include <hip/hip_bf16.h>
#include <stdint.h>

typedef __attribute__((ext_vector_type(4))) float   f32x4;
typedef __attribute__((ext_vector_type(8))) __bf16  bf16x8;
typedef __attribute__((ext_vector_type(4))) __bf16  bf16x4;
typedef __attribute__((ext_vector_type(8))) short   s16x8;
typedef __attribute__((ext_vector_type(4))) unsigned short u16x4;
typedef __attribute__((ext_vector_type(4))) float   fl4;

#define DEVFN static __device__ __forceinline__

constexpr int BATCH = 2, SEQ = 2048, HID = 2048, NHEAD = 16, HDIM = 128;
constexpr int MROWS = BATCH * SEQ;   // 4096
constexpr int N3    = 3 * HID;       // 6144
constexpr float ATT_SCALE = 0.08838834764831845f;  // 1/sqrt(128)
constexpr float LOG2E = 1.44269504088896340736f;

DEVFN unsigned short f2bf(float f) {  // RNE float->bf16
  unsigned int u = __float_as_uint(f);
  u += 0x7FFFu + ((u >> 16) & 1u);
  return (unsigned short)(u >> 16);
}
DEVFN float bf2f(unsigned short h) { return __uint_as_float(((unsigned int)h) << 16); }

DEVFN void async_cp16(const void* g, void* l) {
  __builtin_amdgcn_global_load_lds(
      (__attribute__((address_space(1))) void*)g,
      (__attribute__((address_space(3))) void*)l, 16, 0, 0);
}

DEVFN f32x4 mfma_bf16(bf16x8 a, bf16x8 b, f32x4 c) {
  return __builtin_amdgcn_mfma_f32_16x16x32_bf16(a, b, c, 0, 0, 0);
}

// ---------------------------------------------------------------- fp32 -> bf16 (RNE)
__global__ __launch_bounds__(256) void cvt_bf16(const float* __restrict__ x,
                                                unsigned short* __restrict__ hi, int n4) {
  for (int i = blockIdx.x * blockDim.x + threadIdx.x; i < n4; i += gridDim.x * blockDim.x) {
    fl4 v = ((const fl4*)x)[i];
    u16x4 h;
#pragma unroll
    for (int j = 0; j < 4; j++) h[j] = f2bf(v[j]);
    ((u16x4*)hi)[i] = h;
  }
}

// ---------------------------------------------------------------- transpose + cvt W[R][C] -> T[C][R] bf16
__global__ __launch_bounds__(256) void cvt_transpose(const float* __restrict__ W,
                                                     unsigned short* __restrict__ T,
                                                     int R, int C) {
  __shared__ float tile[32][33];
  const int c0 = blockIdx.x * 32, r0 = blockIdx.y * 32;
  const int tx = threadIdx.x, ty = threadIdx.y;  // (32,8)
#pragma unroll
  for (int i = 0; i < 4; i++) tile[ty + 8 * i][tx] = W[(size_t)(r0 + ty + 8 * i) * C + c0 + tx];
  __syncthreads();
#pragma unroll
  for (int i = 0; i < 4; i++) {
    const float v = tile[tx][ty + 8 * i];
    T[(size_t)(c0 + ty + 8 * i) * R + r0 + tx] = f2bf(v);
  }
}

// ---------------------------------------------------------------- ring-pipelined GEMM (proven r7)
template <bool OUT_BF16>
__global__ __launch_bounds__(512, 1) void gemm_ring(const unsigned short* __restrict__ A,
                                                    const unsigned short* __restrict__ Bt,
                                                    const float* __restrict__ bias,
                                                    void* __restrict__ Cout, int Ndim) {
  constexpr int KDIM  = 2048;
  constexpr int NT    = KDIM / 64;        // 32 K-tiles
  constexpr int ASLOT = 256 * 64;
  constexpr int BSLOT = 128 * 64;
  constexpr int SLOT  = ASLOT + BSLOT;
  __shared__ __align__(16) unsigned short smem[3 * SLOT];  // 144 KB

  const int tid = threadIdx.x;
  const int wid = tid >> 6, lane = tid & 63;
  const int wm = wid >> 2, wn = wid & 3;
  const int g = lane >> 4, q = lane & 15;
  const int n0 = blockIdx.x * 128, m0 = blockIdx.y * 256;

  const int srow = (wid << 3) + (lane >> 3);
  const int scol = (((lane & 7) ^ (lane >> 3)) << 4);
  const char* gA = (const char*)A  + ((size_t)(m0 + srow) * KDIM) * 2 + scol;
  const char* gB = (const char*)Bt + ((size_t)(n0 + srow) * KDIM) * 2 + scol;
  const int dbase = ((wid << 3)) << 7;

  f32x4 acc[8][2] = {};
  const int axor = (q & 7) << 4;

  auto STAGE = [&](int tt, int slot) {
    char* sA = (char*)(smem + slot * SLOT);
    char* sB = (char*)(smem + slot * SLOT + ASLOT);
    const size_t koff = (size_t)tt << 7;
#pragma unroll
    for (int i = 0; i < 4; i++)
      async_cp16(gA + (size_t)(i * 64) * (KDIM * 2) + koff, sA + dbase + (i << 13));
#pragma unroll
    for (int i = 0; i < 2; i++)
      async_cp16(gB + (size_t)(i * 64) * (KDIM * 2) + koff, sB + dbase + (i << 13));
  };

  auto COMPUTE = [&](int slot) {
    const char* sA = (const char*)(smem + slot * SLOT);
    const char* sB = (const char*)(smem + slot * SLOT + ASLOT);
#pragma unroll
    for (int ks = 0; ks < 2; ks++) {
      const int kb = (ks << 6) + (g << 4);
      bf16x8 av[8], bv[2];
#pragma unroll
      for (int nf = 0; nf < 2; nf++) {
        const int row = (wn << 5) + (nf << 4) + q;
        bv[nf] = *(const bf16x8*)(sB + (row << 7) + (kb ^ axor));
      }
#pragma unroll
      for (int mf = 0; mf < 8; mf++) {
        const int row = (wm << 7) + (mf << 4) + q;
        av[mf] = *(const bf16x8*)(sA + (row << 7) + (kb ^ axor));
      }
#pragma unroll
      for (int mf = 0; mf < 8; mf++)
#pragma unroll
        for (int nf = 0; nf < 2; nf++)
          acc[mf][nf] = mfma_bf16(av[mf], bv[nf], acc[mf][nf]);
    }
  };

  STAGE(0, 0);
  STAGE(1, 1);
  int s2 = 2, sc = 0;
#pragma unroll 1
  for (int t = 0; t < NT - 2; ++t) {
    asm volatile("s_waitcnt vmcnt(6)" ::: "memory");
    __builtin_amdgcn_s_barrier();
    asm volatile("" ::: "memory");
    STAGE(t + 2, s2);
    COMPUTE(sc);
    s2 = (s2 == 2) ? 0 : s2 + 1;
    sc = (sc == 2) ? 0 : sc + 1;
  }
  asm volatile("s_waitcnt vmcnt(6)" ::: "memory");
  __builtin_amdgcn_s_barrier();
  asm volatile("" ::: "memory");
  COMPUTE(sc);
  sc = (sc == 2) ? 0 : sc + 1;
  asm volatile("s_waitcnt vmcnt(0)" ::: "memory");
  __builtin_amdgcn_s_barrier();
  asm volatile("" ::: "memory");
  COMPUTE(sc);

  float bvv[2];
#pragma unroll
  for (int nf = 0; nf < 2; nf++) bvv[nf] = bias[n0 + (wn << 5) + (nf << 4) + q];
#pragma unroll
  for (int mf = 0; mf < 8; mf++) {
    const int rowg = m0 + (wm << 7) + (mf << 4) + (g << 2);
#pragma unroll
    for (int nf = 0; nf < 2; nf++) {
      const int colg = n0 + (wn << 5) + (nf << 4) + q;
#pragma unroll
      for (int r = 0; r < 4; r++) {
        const float v = acc[mf][nf][r] + bvv[nf];
        if (OUT_BF16)
          ((unsigned short*)Cout)[(size_t)(rowg + r) * Ndim + colg] = f2bf(v);
        else
          ((float*)Cout)[(size_t)(rowg + r) * Ndim + colg] = v;
      }
    }
  }
}

// ---------------------------------------------------------------- V slice of QKV -> V^T [z][d][s]
__global__ __launch_bounds__(256) void transpose_v(const unsigned short* __restrict__ qkv,
                                                   unsigned short* __restrict__ vt) {
  __shared__ __align__(16) unsigned short tile[64][136];
  const int z = blockIdx.y, b = z >> 4, h = z & 15;
  const int s0 = blockIdx.x << 6;
  const int t = threadIdx.x;
#pragma unroll
  for (int i = 0; i < 4; i++) {
    const int idx = t + (i << 8);
    const int row = idx >> 4, ch = idx & 15;
    *(s16x8*)&tile[row][ch << 3] =
        *(const s16x8*)(qkv + (size_t)(b * SEQ + s0 + row) * N3 + 2 * HID + h * HDIM + (ch << 3));
  }
  __syncthreads();
#pragma unroll
  for (int i = 0; i < 4; i++) {
    const int idx = t + (i << 8);
    const int d = idx >> 3, sc = idx & 7;
    s16x8 v;
#pragma unroll
    for (int j = 0; j < 8; j++) v[j] = (short)tile[(sc << 3) + j][d];
    *(s16x8*)(vt + (size_t)(z * HDIM + d) * SEQ + s0 + (sc << 3)) = v;
  }
}

// ---------------------------------------------------------------- flash attention, ring-staged K/V
// 8 waves x 32 q-rows (2 q-sets of 16). 3-slot K/V LDS ring, counted vmcnt(4),
// one raw barrier per tile (T3/T4). T1: same-z blocks grouped per XCD (K/V fit L2).
__global__ __launch_bounds__(512, 2) void attn_kernel(const unsigned short* __restrict__ qkv,
                                                      const unsigned short* __restrict__ vt,
                                                      const float* __restrict__ mask,
                                                      unsigned short* __restrict__ ctx) {
  constexpr int NT    = SEQ / 64;           // 32 K/V tiles
  constexpr int KSLOT = 64 * 128;           // shorts
  constexpr int VSLOT = 128 * 64;
  constexpr int SLOT  = KSLOT + VSLOT;      // 32 KB
  __shared__ __align__(16) unsigned short sKV[3 * SLOT];   // 96 KB
  __shared__ __align__(16) unsigned short sP[8][32 * 72];  // 36 KB, 144B rows

  // T1 swizzle: 256 blocks; XCD = bid%8 hosts z in [xcd*4, xcd*4+4) -> 4MB K/V = one L2
  const int bid = blockIdx.x;
  const int z  = ((bid & 7) << 2) + ((bid >> 3) >> 3);
  const int qb = (bid >> 3) & 7;
  const int b = z >> 4, h = z & 15;
  const int tid = threadIdx.x, wid = tid >> 6, lane = tid & 63;
  const int g = lane >> 4, q = lane & 15;
  const int q0 = (qb << 8) + (wid << 5);    // 256 q-rows/block, 32/wave

  bf16x8 bq[2][4];  // Q B-frags: lane supplies Q[q][d = c*32 + g*8 + j]
#pragma unroll
  for (int qs = 0; qs < 2; qs++) {
    const unsigned short* qrow = qkv + (size_t)(b * SEQ + q0 + (qs << 4) + q) * N3 + h * HDIM;
#pragma unroll
    for (int c = 0; c < 4; c++) bq[qs][c] = *(const bf16x8*)(qrow + (c << 5) + (g << 3));
  }

  f32x4 acc[2][8] = {};
  float mrun[2] = {-1e30f, -1e30f}, lrun[2] = {0.f, 0.f};
  unsigned short* myP = &sP[wid][0];
  const int sbase = (lane & 48) | (g << 2);

  // staging bases (per thread); dst is wave-uniform, HW adds lane*16
  const char* gK = (const char*)qkv + ((size_t)(b * SEQ) * N3 + HID + h * HDIM) * 2;
  const char* gV = (const char*)vt + ((size_t)z * HDIM * SEQ) * 2;

  auto STAGE = [&](int tt, int slot) {
    char* base = (char*)(sKV + slot * SLOT);
    const int k0 = tt << 6;
#pragma unroll
    for (int i = 0; i < 2; i++) {
      const int krow = (i << 5) + (tid >> 4);                       // 0..63
      const int kc = (((tid & 15) << 4)) ^ ((krow & 7) << 4);       // pre-swizzled src col
      async_cp16(gK + ((size_t)(k0 + krow) * N3) * 2 + kc, base + (i << 13) + (wid << 10));
    }
#pragma unroll
    for (int i = 0; i < 2; i++) {
      const int vrow = (i << 6) + (tid >> 3);                       // 0..127
      const int vc = (((tid & 7) << 4)) ^ ((vrow & 7) << 4);
      async_cp16(gV + ((size_t)vrow * SEQ + k0) * 2 + vc,
                 base + (KSLOT * 2) + (i << 13) + (wid << 10));
    }
  };

  auto COMPUTE = [&](int t, int slot) {
    const char* sK = (const char*)(sKV + slot * SLOT);
    const char* sV = (const char*)(sKV + slot * SLOT + KSLOT);
    const int k0 = t << 6;

    // S^T = K * Q^T (swapped): C col = q, row = key = kt*16 + 4g + r; ak shared by q-sets
    f32x4 accs[2][4];
#pragma unroll
    for (int qs = 0; qs < 2; qs++)
#pragma unroll
      for (int kt = 0; kt < 4; kt++) accs[qs][kt] = (f32x4){0.f, 0.f, 0.f, 0.f};
#pragma unroll
    for (int c = 0; c < 4; c++) {
      const int kbyte = (c << 6) + (g << 4);
#pragma unroll
      for (int kt = 0; kt < 4; kt++) {
        const int key = (kt << 4) + q;
        const bf16x8 ak = *(const bf16x8*)(sK + (key << 8) + (kbyte ^ ((key & 7) << 4)));
        accs[0][kt] = mfma_bf16(ak, bq[0][c], accs[0][kt]);
        accs[1][kt] = mfma_bf16(ak, bq[1][c], accs[1][kt]);
      }
    }

    // online softmax per q-set
#pragma unroll
    for (int qs = 0; qs < 2; qs++) {
      float sv[4][4];
      float mt = -1e30f;
#pragma unroll
      for (int kt = 0; kt < 4; kt++) {
        const fl4 mk = *(const fl4*)(mask + (size_t)b * SEQ + k0 + (kt << 4) + (g << 2));
#pragma unroll
        for (int r = 0; r < 4; r++) {
          const float s = accs[qs][kt][r] * ATT_SCALE + mk[r];
          sv[kt][r] = s;
          mt = fmaxf(mt, s);
        }
      }
      mt = fmaxf(mt, __shfl_xor(mt, 16));
      mt = fmaxf(mt, __shfl_xor(mt, 32));
      if (!__all(mt <= mrun[qs] + 8.f)) {    // defer-max (T13)
        const float mnew = fmaxf(mrun[qs], mt);
        const float fs = exp2f((mrun[qs] - mnew) * LOG2E);
        lrun[qs] *= fs;
#pragma unroll
        for (int r = 0; r < 4; r++) {
          const float fr = __shfl(fs, sbase + r);
#pragma unroll
          for (int dt = 0; dt < 8; dt++) acc[qs][dt][r] *= fr;
        }
        mrun[qs] = mnew;
      }
      float ps = 0.f;
#pragma unroll
      for (int kt = 0; kt < 4; kt++) {
        bf16x4 pk;
#pragma unroll
        for (int r = 0; r < 4; r++) {
          const float e = exp2f((sv[kt][r] - mrun[qs]) * LOG2E);
          ps += e;
          pk[r] = (__bf16)e;
        }
        *(bf16x4*)((char*)myP + ((qs << 4) + q) * 144 + (((kt << 4) + (g << 2)) << 1)) = pk;
      }
      ps += __shfl_xor(ps, 16);
      ps += __shfl_xor(ps, 32);
      lrun[qs] += ps;
    }

    // fence P stores vs P loads (TBAA + rule #18); sP is wave-private, no barrier needed
    asm volatile("s_waitcnt lgkmcnt(0)" ::: "memory");
    __builtin_amdgcn_sched_barrier(0);

    // ctx += P * V
#pragma unroll
    for (int kc = 0; kc < 2; kc++) {
      const bf16x8 pa0 = *(const bf16x8*)((const char*)myP + q * 144 + (kc << 6) + (g << 4));
      const bf16x8 pa1 = *(const bf16x8*)((const char*)myP + (16 + q) * 144 + (kc << 6) + (g << 4));
      const int kbyte = (kc << 6) + (g << 4);
#pragma unroll
      for (int dt = 0; dt < 8; dt++) {
        const int d = (dt << 4) + q;
        const bf16x8 bvv = *(const bf16x8*)(sV + (d << 7) + (kbyte ^ ((d & 7) << 4)));
        acc[0][dt] = mfma_bf16(pa0, bvv, acc[0][dt]);
        acc[1][dt] = mfma_bf16(pa1, bvv, acc[1][dt]);
      }
    }
  };

  // ring main loop (same safety argument as gemm_ring)
  STAGE(0, 0);
  STAGE(1, 1);
  int s2 = 2, sc = 0;
#pragma unroll 1
  for (int t = 0; t < NT - 2; ++t) {
    asm volatile("s_waitcnt vmcnt(4)" ::: "memory");   // my tile-t loads landed (t+1 may fly)
    __builtin_amdgcn_s_barrier();                      // => all threads' tile-t loads landed
    asm volatile("" ::: "memory");
    STAGE(t + 2, s2);
    COMPUTE(t, sc);
    s2 = (s2 == 2) ? 0 : s2 + 1;
    sc = (sc == 2) ? 0 : sc + 1;
  }
  asm volatile("s_waitcnt vmcnt(4)" ::: "memory");
  __builtin_amdgcn_s_barrier();
  asm volatile("" ::: "memory");
  COMPUTE(NT - 2, sc);
  sc = (sc == 2) ? 0 : sc + 1;
  asm volatile("s_waitcnt vmcnt(0)" ::: "memory");
  __builtin_amdgcn_s_barrier();
  asm volatile("" ::: "memory");
  COMPUTE(NT - 1, sc);

#pragma unroll
  for (int qs = 0; qs < 2; qs++)
#pragma unroll
    for (int r = 0; r < 4; r++) {
      const float lr = __shfl(lrun[qs], sbase + r);
      const float inv = 1.f / lr;
      const int token = b * SEQ + q0 + (qs << 4) + (g << 2) + r;
      unsigned short* crow = ctx + (size_t)token * HID + h * HDIM + q;
#pragma unroll
      for (int dt = 0; dt < 8; dt++) crow[dt << 4] = f2bf(acc[qs][dt][r] * inv);
    }
}

// ---------------------------------------------------------------- launch
extern "C" void kernel_launch(void* const* d_in, const int* in_sizes, int n_in,
                              void* d_out, int out_size, void* d_ws, size_t ws_size,
                              hipStream_t stream) {
  const float* hs   = (const float*)d_in[0];
  const float* mask = (const float*)d_in[1];
  const float* Wqkv = (const float*)d_in[2];
  const float* bqkv = (const float*)d_in[3];
  const float* Wout = (const float*)d_in[4];
  const float* bout = (const float*)d_in[5];

  char* ws = (char*)d_ws;
  size_t off = 0;
  auto alloc = [&](size_t n) { char* p = ws + off; off += (n + 255) & ~(size_t)255; return p; };
  unsigned short* hs_bf = (unsigned short*)alloc((size_t)MROWS * HID * 2);
  unsigned short* wq_bf = (unsigned short*)alloc((size_t)N3 * HID * 2);
  unsigned short* wo_bf = (unsigned short*)alloc((size_t)HID * HID * 2);
  unsigned short* qkvb  = (unsigned short*)alloc((size_t)MROWS * N3 * 2);
  unsigned short* vtb   = (unsigned short*)alloc((size_t)BATCH * NHEAD * HDIM * SEQ * 2);
  unsigned short* ctxb  = (unsigned short*)alloc((size_t)MROWS * HID * 2);
  (void)ws_size;

  cvt_bf16<<<2048, 256, 0, stream>>>(hs, hs_bf, MROWS * HID / 4);
  dim3 tb(32, 8);
  cvt_transpose<<<dim3(N3 / 32, HID / 32), tb, 0, stream>>>(Wqkv, wq_bf, HID, N3);
  cvt_transpose<<<dim3(HID / 32, HID / 32), tb, 0, stream>>>(Wout, wo_bf, HID, HID);
  gemm_ring<true ><<<dim3(N3 / 128, MROWS / 256), 512, 0, stream>>>(hs_bf, wq_bf, bqkv, qkvb, N3);
  transpose_v<<<dim3(SEQ / 64, BATCH * NHEAD), 256, 0, stream>>>(qkvb, vtb);
  attn_kernel<<<256, 512, 0, stream>>>(qkvb, vtb, mask, ctxb);
  gemm_ring<false><<<dim3(HID / 128, MROWS / 256), 512, 0, stream>>>(ctxb, wo_bf, bout, (float*)d_out, HID);
}

// Round 9
// 272.562 us; speedup vs baseline: 1.7775x; 1.0180x over previous
//
#include <hip/hip_runtime.h>
#include <hip/hip_bf16.h>
#include <stdint.h>

typedef __attribute__((ext_vector_type(4))) float   f32x4;
typedef __attribute__((ext_vector_type(8))) __bf16  bf16x8;
typedef __attribute__((ext_vector_type(4))) __bf16  bf16x4;
typedef __attribute__((ext_vector_type(8))) short   s16x8;
typedef __attribute__((ext_vector_type(4))) unsigned short u16x4;
typedef __attribute__((ext_vector_type(4))) float   fl4;

#define DEVFN static __device__ __forceinline__

constexpr int BATCH = 2, SEQ = 2048, HID = 2048, NHEAD = 16, HDIM = 128;
constexpr int MROWS = BATCH * SEQ;   // 4096
constexpr int N3    = 3 * HID;       // 6144
constexpr float LOG2E = 1.44269504088896340736f;
constexpr float SCALE_LOG2E = 0.12751649736170852f;   // (1/sqrt(128)) * log2(e)
constexpr float DEFER_THR = 11.541560327111708f;      // 8 * log2(e)

DEVFN unsigned short f2bf(float f) {  // RNE float->bf16
  unsigned int u = __float_as_uint(f);
  u += 0x7FFFu + ((u >> 16) & 1u);
  return (unsigned short)(u >> 16);
}
DEVFN float bf2f(unsigned short h) { return __uint_as_float(((unsigned int)h) << 16); }

DEVFN void async_cp16(const void* g, void* l) {
  __builtin_amdgcn_global_load_lds(
      (__attribute__((address_space(1))) void*)g,
      (__attribute__((address_space(3))) void*)l, 16, 0, 0);
}

DEVFN f32x4 mfma_bf16(bf16x8 a, bf16x8 b, f32x4 c) {
  return __builtin_amdgcn_mfma_f32_16x16x32_bf16(a, b, c, 0, 0, 0);
}

// ---------------------------------------------------------------- fp32 -> bf16 (RNE)
__global__ __launch_bounds__(256) void cvt_bf16(const float* __restrict__ x,
                                                unsigned short* __restrict__ hi, int n4) {
  for (int i = blockIdx.x * blockDim.x + threadIdx.x; i < n4; i += gridDim.x * blockDim.x) {
    fl4 v = ((const fl4*)x)[i];
    u16x4 h;
#pragma unroll
    for (int j = 0; j < 4; j++) h[j] = f2bf(v[j]);
    ((u16x4*)hi)[i] = h;
  }
}

// ---------------------------------------------------------------- transpose + cvt W[R][C] -> T[C][R] bf16
__global__ __launch_bounds__(256) void cvt_transpose(const float* __restrict__ W,
                                                     unsigned short* __restrict__ T,
                                                     int R, int C) {
  __shared__ float tile[32][33];
  const int c0 = blockIdx.x * 32, r0 = blockIdx.y * 32;
  const int tx = threadIdx.x, ty = threadIdx.y;  // (32,8)
#pragma unroll
  for (int i = 0; i < 4; i++) tile[ty + 8 * i][tx] = W[(size_t)(r0 + ty + 8 * i) * C + c0 + tx];
  __syncthreads();
#pragma unroll
  for (int i = 0; i < 4; i++) {
    const float v = tile[tx][ty + 8 * i];
    T[(size_t)(c0 + ty + 8 * i) * R + r0 + tx] = f2bf(v);
  }
}

// ---------------------------------------------------------------- ring-pipelined GEMM (proven r7)
template <bool OUT_BF16>
__global__ __launch_bounds__(512, 1) void gemm_ring(const unsigned short* __restrict__ A,
                                                    const unsigned short* __restrict__ Bt,
                                                    const float* __restrict__ bias,
                                                    void* __restrict__ Cout, int Ndim) {
  constexpr int KDIM  = 2048;
  constexpr int NT    = KDIM / 64;
  constexpr int ASLOT = 256 * 64;
  constexpr int BSLOT = 128 * 64;
  constexpr int SLOT  = ASLOT + BSLOT;
  __shared__ __align__(16) unsigned short smem[3 * SLOT];  // 144 KB

  const int tid = threadIdx.x;
  const int wid = tid >> 6, lane = tid & 63;
  const int wm = wid >> 2, wn = wid & 3;
  const int g = lane >> 4, q = lane & 15;
  const int n0 = blockIdx.x * 128, m0 = blockIdx.y * 256;

  const int srow = (wid << 3) + (lane >> 3);
  const int scol = (((lane & 7) ^ (lane >> 3)) << 4);
  const char* gA = (const char*)A  + ((size_t)(m0 + srow) * KDIM) * 2 + scol;
  const char* gB = (const char*)Bt + ((size_t)(n0 + srow) * KDIM) * 2 + scol;
  const int dbase = ((wid << 3)) << 7;

  f32x4 acc[8][2] = {};
  const int axor = (q & 7) << 4;

  auto STAGE = [&](int tt, int slot) {
    char* sA = (char*)(smem + slot * SLOT);
    char* sB = (char*)(smem + slot * SLOT + ASLOT);
    const size_t koff = (size_t)tt << 7;
#pragma unroll
    for (int i = 0; i < 4; i++)
      async_cp16(gA + (size_t)(i * 64) * (KDIM * 2) + koff, sA + dbase + (i << 13));
#pragma unroll
    for (int i = 0; i < 2; i++)
      async_cp16(gB + (size_t)(i * 64) * (KDIM * 2) + koff, sB + dbase + (i << 13));
  };

  auto COMPUTE = [&](int slot) {
    const char* sA = (const char*)(smem + slot * SLOT);
    const char* sB = (const char*)(smem + slot * SLOT + ASLOT);
#pragma unroll
    for (int ks = 0; ks < 2; ks++) {
      const int kb = (ks << 6) + (g << 4);
      bf16x8 av[8], bv[2];
#pragma unroll
      for (int nf = 0; nf < 2; nf++) {
        const int row = (wn << 5) + (nf << 4) + q;
        bv[nf] = *(const bf16x8*)(sB + (row << 7) + (kb ^ axor));
      }
#pragma unroll
      for (int mf = 0; mf < 8; mf++) {
        const int row = (wm << 7) + (mf << 4) + q;
        av[mf] = *(const bf16x8*)(sA + (row << 7) + (kb ^ axor));
      }
#pragma unroll
      for (int mf = 0; mf < 8; mf++)
#pragma unroll
        for (int nf = 0; nf < 2; nf++)
          acc[mf][nf] = mfma_bf16(av[mf], bv[nf], acc[mf][nf]);
    }
  };

  STAGE(0, 0);
  STAGE(1, 1);
  int s2 = 2, sc = 0;
#pragma unroll 1
  for (int t = 0; t < NT - 2; ++t) {
    asm volatile("s_waitcnt vmcnt(6)" ::: "memory");
    __builtin_amdgcn_s_barrier();
    asm volatile("" ::: "memory");
    STAGE(t + 2, s2);
    COMPUTE(sc);
    s2 = (s2 == 2) ? 0 : s2 + 1;
    sc = (sc == 2) ? 0 : sc + 1;
  }
  asm volatile("s_waitcnt vmcnt(6)" ::: "memory");
  __builtin_amdgcn_s_barrier();
  asm volatile("" ::: "memory");
  COMPUTE(sc);
  sc = (sc == 2) ? 0 : sc + 1;
  asm volatile("s_waitcnt vmcnt(0)" ::: "memory");
  __builtin_amdgcn_s_barrier();
  asm volatile("" ::: "memory");
  COMPUTE(sc);

  float bvv[2];
#pragma unroll
  for (int nf = 0; nf < 2; nf++) bvv[nf] = bias[n0 + (wn << 5) + (nf << 4) + q];
#pragma unroll
  for (int mf = 0; mf < 8; mf++) {
    const int rowg = m0 + (wm << 7) + (mf << 4) + (g << 2);
#pragma unroll
    for (int nf = 0; nf < 2; nf++) {
      const int colg = n0 + (wn << 5) + (nf << 4) + q;
#pragma unroll
      for (int r = 0; r < 4; r++) {
        const float v = acc[mf][nf][r] + bvv[nf];
        if (OUT_BF16)
          ((unsigned short*)Cout)[(size_t)(rowg + r) * Ndim + colg] = f2bf(v);
        else
          ((float*)Cout)[(size_t)(rowg + r) * Ndim + colg] = v;
      }
    }
  }
}

// ---------------------------------------------------------------- V slice of QKV -> V^T [z][d][s]
__global__ __launch_bounds__(256) void transpose_v(const unsigned short* __restrict__ qkv,
                                                   unsigned short* __restrict__ vt) {
  __shared__ __align__(16) unsigned short tile[64][136];
  const int z = blockIdx.y, b = z >> 4, h = z & 15;
  const int s0 = blockIdx.x << 6;
  const int t = threadIdx.x;
#pragma unroll
  for (int i = 0; i < 4; i++) {
    const int idx = t + (i << 8);
    const int row = idx >> 4, ch = idx & 15;
    *(s16x8*)&tile[row][ch << 3] =
        *(const s16x8*)(qkv + (size_t)(b * SEQ + s0 + row) * N3 + 2 * HID + h * HDIM + (ch << 3));
  }
  __syncthreads();
#pragma unroll
  for (int i = 0; i < 4; i++) {
    const int idx = t + (i << 8);
    const int d = idx >> 3, sc = idx & 7;
    s16x8 v;
#pragma unroll
    for (int j = 0; j < 8; j++) v[j] = (short)tile[(sc << 3) + j][d];
    *(s16x8*)(vt + (size_t)(z * HDIM + d) * SEQ + s0 + (sc << 3)) = v;
  }
}

// ---------------------------------------------------------------- flash attention, ring-staged K/V
// 8 waves x 32 q-rows. 3-slot K/V ring + counted vmcnt (T3/T4); NO VMEM inside the
// tile loop (mask pre-staged to LDS x LOG2E) so the compiler cannot inject vmcnt(0).
// log2-domain softmax. T1: same-z blocks grouped per XCD.
__global__ __launch_bounds__(512, 2) void attn_kernel(const unsigned short* __restrict__ qkv,
                                                      const unsigned short* __restrict__ vt,
                                                      const float* __restrict__ mask,
                                                      unsigned short* __restrict__ ctx) {
  constexpr int NT    = SEQ / 64;
  constexpr int KSLOT = 64 * 128;           // shorts (16 KB)
  constexpr int VSLOT = 128 * 64;
  constexpr int SLOT  = KSLOT + VSLOT;      // 32 KB
  __shared__ __align__(16) unsigned short sKV[3 * SLOT];   // 96 KB
  __shared__ __align__(16) unsigned short sP[8][32 * 72];  // 36 KB
  __shared__ __align__(16) float sM[SEQ];                  // 8 KB: mask * LOG2E

  const int bid = blockIdx.x;
  const int z  = ((bid & 7) << 2) + ((bid >> 3) >> 3);
  const int qb = (bid >> 3) & 7;
  const int b = z >> 4, h = z & 15;
  const int tid = threadIdx.x, wid = tid >> 6, lane = tid & 63;
  const int g = lane >> 4, q = lane & 15;
  const int q0 = (qb << 8) + (wid << 5);

  // mask -> LDS (x LOG2E), once. 512 threads x fl4 = 2048 floats.
  {
    fl4 m = ((const fl4*)(mask + (size_t)b * SEQ))[tid];
    m *= LOG2E;
    ((fl4*)sM)[tid] = m;
  }

  bf16x8 bq[2][4];
#pragma unroll
  for (int qs = 0; qs < 2; qs++) {
    const unsigned short* qrow = qkv + (size_t)(b * SEQ + q0 + (qs << 4) + q) * N3 + h * HDIM;
#pragma unroll
    for (int c = 0; c < 4; c++) bq[qs][c] = *(const bf16x8*)(qrow + (c << 5) + (g << 3));
  }

  f32x4 acc[2][8] = {};
  float mrun[2] = {-1e30f, -1e30f}, lrun[2] = {0.f, 0.f};
  unsigned short* myP = &sP[wid][0];
  const int sbase = (lane & 48) | (g << 2);

  const char* gK = (const char*)qkv + ((size_t)(b * SEQ) * N3 + HID + h * HDIM) * 2;
  const char* gV = (const char*)vt + ((size_t)z * HDIM * SEQ) * 2;

  auto STAGE = [&](int tt, int slot) {
    char* base = (char*)(sKV + slot * SLOT);
    const int k0 = tt << 6;
#pragma unroll
    for (int i = 0; i < 2; i++) {
      const int krow = (i << 5) + (tid >> 4);
      const int kc = (((tid & 15) << 4)) ^ ((krow & 7) << 4);
      async_cp16(gK + ((size_t)(k0 + krow) * N3) * 2 + kc, base + (i << 13) + (wid << 10));
    }
#pragma unroll
    for (int i = 0; i < 2; i++) {
      const int vrow = (i << 6) + (tid >> 3);
      const int vc = (((tid & 7) << 4)) ^ ((vrow & 7) << 4);
      async_cp16(gV + ((size_t)vrow * SEQ + k0) * 2 + vc,
                 base + (KSLOT * 2) + (i << 13) + (wid << 10));
    }
  };

  auto COMPUTE = [&](int t, int slot) {
    const char* sK = (const char*)(sKV + slot * SLOT);
    const char* sV = (const char*)(sKV + slot * SLOT + KSLOT);
    const int k0 = t << 6;

    // S^T = K * Q^T (swapped); ak shared by both q-sets
    f32x4 accs[2][4];
#pragma unroll
    for (int qs = 0; qs < 2; qs++)
#pragma unroll
      for (int kt = 0; kt < 4; kt++) accs[qs][kt] = (f32x4){0.f, 0.f, 0.f, 0.f};
#pragma unroll
    for (int c = 0; c < 4; c++) {
      const int kbyte = (c << 6) + (g << 4);
#pragma unroll
      for (int kt = 0; kt < 4; kt++) {
        const int key = (kt << 4) + q;
        const bf16x8 ak = *(const bf16x8*)(sK + (key << 8) + (kbyte ^ ((key & 7) << 4)));
        accs[0][kt] = mfma_bf16(ak, bq[0][c], accs[0][kt]);
        accs[1][kt] = mfma_bf16(ak, bq[1][c], accs[1][kt]);
      }
    }

    // mask (log2 domain) from LDS, shared by both q-sets
    fl4 mk2[4];
#pragma unroll
    for (int kt = 0; kt < 4; kt++) mk2[kt] = *(const fl4*)&sM[k0 + (kt << 4) + (g << 2)];

    // log2-domain online softmax per q-set
#pragma unroll
    for (int qs = 0; qs < 2; qs++) {
      float s2[4][4];
      float km[4];
#pragma unroll
      for (int kt = 0; kt < 4; kt++) {
#pragma unroll
        for (int r = 0; r < 4; r++)
          s2[kt][r] = fmaf(accs[qs][kt][r], SCALE_LOG2E, mk2[kt][r]);
        km[kt] = fmaxf(fmaxf(s2[kt][0], s2[kt][1]), fmaxf(s2[kt][2], s2[kt][3]));
      }
      float mt = fmaxf(fmaxf(km[0], km[1]), fmaxf(km[2], km[3]));
      mt = fmaxf(mt, __shfl_xor(mt, 16));
      mt = fmaxf(mt, __shfl_xor(mt, 32));
      if (!__all(mt <= mrun[qs] + DEFER_THR)) {   // defer-max (T13)
        const float mnew = fmaxf(mrun[qs], mt);
        const float fs = exp2f(mrun[qs] - mnew);
        lrun[qs] *= fs;
#pragma unroll
        for (int r = 0; r < 4; r++) {
          const float fr = __shfl(fs, sbase + r);
#pragma unroll
          for (int dt = 0; dt < 8; dt++) acc[qs][dt][r] *= fr;
        }
        mrun[qs] = mnew;
      }
      float pst[4];
#pragma unroll
      for (int kt = 0; kt < 4; kt++) {
        bf16x4 pk;
        float e0 = exp2f(s2[kt][0] - mrun[qs]);
        float e1 = exp2f(s2[kt][1] - mrun[qs]);
        float e2 = exp2f(s2[kt][2] - mrun[qs]);
        float e3 = exp2f(s2[kt][3] - mrun[qs]);
        pk[0] = (__bf16)e0; pk[1] = (__bf16)e1; pk[2] = (__bf16)e2; pk[3] = (__bf16)e3;
        pst[kt] = (e0 + e1) + (e2 + e3);
        *(bf16x4*)((char*)myP + ((qs << 4) + q) * 144 + (((kt << 4) + (g << 2)) << 1)) = pk;
      }
      float ps = (pst[0] + pst[1]) + (pst[2] + pst[3]);
      ps += __shfl_xor(ps, 16);
      ps += __shfl_xor(ps, 32);
      lrun[qs] += ps;
    }

    // fence P stores vs P loads (TBAA + rule #18); sP is wave-private
    asm volatile("s_waitcnt lgkmcnt(0)" ::: "memory");
    __builtin_amdgcn_sched_barrier(0);

    // ctx += P * V
#pragma unroll
    for (int kc = 0; kc < 2; kc++) {
      const bf16x8 pa0 = *(const bf16x8*)((const char*)myP + q * 144 + (kc << 6) + (g << 4));
      const bf16x8 pa1 = *(const bf16x8*)((const char*)myP + (16 + q) * 144 + (kc << 6) + (g << 4));
      const int kbyte = (kc << 6) + (g << 4);
#pragma unroll
      for (int dt = 0; dt < 8; dt++) {
        const int d = (dt << 4) + q;
        const bf16x8 bvv = *(const bf16x8*)(sV + (d << 7) + (kbyte ^ ((d & 7) << 4)));
        acc[0][dt] = mfma_bf16(pa0, bvv, acc[0][dt]);
        acc[1][dt] = mfma_bf16(pa1, bvv, acc[1][dt]);
      }
    }
  };

  STAGE(0, 0);
  STAGE(1, 1);
  __syncthreads();       // sM visible to all waves (also orders ring slot reuse start)
  int s2 = 2, sc = 0;
#pragma unroll 1
  for (int t = 0; t < NT - 2; ++t) {
    asm volatile("s_waitcnt vmcnt(4)" ::: "memory");
    __builtin_amdgcn_s_barrier();
    asm volatile("" ::: "memory");
    STAGE(t + 2, s2);
    COMPUTE(t, sc);
    s2 = (s2 == 2) ? 0 : s2 + 1;
    sc = (sc == 2) ? 0 : sc + 1;
  }
  asm volatile("s_waitcnt vmcnt(4)" ::: "memory");
  __builtin_amdgcn_s_barrier();
  asm volatile("" ::: "memory");
  COMPUTE(NT - 2, sc);
  sc = (sc == 2) ? 0 : sc + 1;
  asm volatile("s_waitcnt vmcnt(0)" ::: "memory");
  __builtin_amdgcn_s_barrier();
  asm volatile("" ::: "memory");
  COMPUTE(NT - 1, sc);

#pragma unroll
  for (int qs = 0; qs < 2; qs++)
#pragma unroll
    for (int r = 0; r < 4; r++) {
      const float lr = __shfl(lrun[qs], sbase + r);
      const float inv = 1.f / lr;
      const int token = b * SEQ + q0 + (qs << 4) + (g << 2) + r;
      unsigned short* crow = ctx + (size_t)token * HID + h * HDIM + q;
#pragma unroll
      for (int dt = 0; dt < 8; dt++) crow[dt << 4] = f2bf(acc[qs][dt][r] * inv);
    }
}

// ---------------------------------------------------------------- launch
extern "C" void kernel_launch(void* const* d_in, const int* in_sizes, int n_in,
                              void* d_out, int out_size, void* d_ws, size_t ws_size,
                              hipStream_t stream) {
  const float* hs   = (const float*)d_in[0];
  const float* mask = (const float*)d_in[1];
  const float* Wqkv = (const float*)d_in[2];
  const float* bqkv = (const float*)d_in[3];
  const float* Wout = (const float*)d_in[4];
  const float* bout = (const float*)d_in[5];

  char* ws = (char*)d_ws;
  size_t off = 0;
  auto alloc = [&](size_t n) { char* p = ws + off; off += (n + 255) & ~(size_t)255; return p; };
  unsigned short* hs_bf = (unsigned short*)alloc((size_t)MROWS * HID * 2);
  unsigned short* wq_bf = (unsigned short*)alloc((size_t)N3 * HID * 2);
  unsigned short* wo_bf = (unsigned short*)alloc((size_t)HID * HID * 2);
  unsigned short* qkvb  = (unsigned short*)alloc((size_t)MROWS * N3 * 2);
  unsigned short* vtb   = (unsigned short*)alloc((size_t)BATCH * NHEAD * HDIM * SEQ * 2);
  unsigned short* ctxb  = (unsigned short*)alloc((size_t)MROWS * HID * 2);
  (void)ws_size;

  cvt_bf16<<<2048, 256, 0, stream>>>(hs, hs_bf, MROWS * HID / 4);
  dim3 tb(32, 8);
  cvt_transpose<<<dim3(N3 / 32, HID / 32), tb, 0, stream>>>(Wqkv, wq_bf, HID, N3);
  cvt_transpose<<<dim3(HID / 32, HID / 32), tb, 0, stream>>>(Wout, wo_bf, HID, HID);
  gemm_ring<true ><<<dim3(N3 / 128, MROWS / 256), 512, 0, stream>>>(hs_bf, wq_bf, bqkv, qkvb, N3);
  transpose_v<<<dim3(SEQ / 64, BATCH * NHEAD), 256, 0, stream>>>(qkvb, vtb);
  attn_kernel<<<256, 512, 0, stream>>>(qkvb, vtb, mask, ctxb);
  gemm_ring<false><<<dim3(HID / 128, MROWS / 256), 512, 0, stream>>>(ctxb, wo_bf, bout, (float*)d_out, HID);
}

// Round 10
// 268.898 us; speedup vs baseline: 1.8017x; 1.0136x over previous
//
#include <hip/hip_runtime.h>
#include <hip/hip_bf16.h>
#include <stdint.h>

typedef __attribute__((ext_vector_type(4)))  float   f32x4;
typedef __attribute__((ext_vector_type(16))) float   f32x16;
typedef __attribute__((ext_vector_type(8)))  __bf16  bf16x8;
typedef __attribute__((ext_vector_type(8)))  short   s16x8;
typedef __attribute__((ext_vector_type(4)))  unsigned short u16x4;
typedef __attribute__((ext_vector_type(4)))  float   fl4;
typedef __attribute__((ext_vector_type(2)))  unsigned int u32x2;
typedef __attribute__((ext_vector_type(4)))  unsigned int u32x4;

#define DEVFN static __device__ __forceinline__

constexpr int BATCH = 2, SEQ = 2048, HID = 2048, NHEAD = 16, HDIM = 128;
constexpr int MROWS = BATCH * SEQ;   // 4096
constexpr int N3    = 3 * HID;       // 6144
constexpr float LOG2E = 1.44269504088896340736f;
constexpr float SCALE_LOG2E = 0.12751649736170852f;   // (1/sqrt(128)) * log2(e)
constexpr float DEFER_THR = 11.541560327111708f;      // 8 * log2(e)

DEVFN unsigned short f2bf(float f) {  // RNE float->bf16
  unsigned int u = __float_as_uint(f);
  u += 0x7FFFu + ((u >> 16) & 1u);
  return (unsigned short)(u >> 16);
}
DEVFN float bf2f(unsigned short h) { return __uint_as_float(((unsigned int)h) << 16); }

DEVFN void async_cp16(const void* g, void* l) {
  __builtin_amdgcn_global_load_lds(
      (__attribute__((address_space(1))) void*)g,
      (__attribute__((address_space(3))) void*)l, 16, 0, 0);
}

DEVFN f32x4 mfma_bf16(bf16x8 a, bf16x8 b, f32x4 c) {
  return __builtin_amdgcn_mfma_f32_16x16x32_bf16(a, b, c, 0, 0, 0);
}
DEVFN f32x16 mfma32(bf16x8 a, bf16x8 b, f32x16 c) {
  return __builtin_amdgcn_mfma_f32_32x32x16_bf16(a, b, c, 0, 0, 0);
}
DEVFN unsigned cvt_pk_bf16(float lo, float hi) {
  unsigned r;
  asm("v_cvt_pk_bf16_f32 %0, %1, %2" : "=v"(r) : "v"(lo), "v"(hi));
  return r;
}

// ---------------------------------------------------------------- fp32 -> bf16 (RNE)
__global__ __launch_bounds__(256) void cvt_bf16(const float* __restrict__ x,
                                                unsigned short* __restrict__ hi, int n4) {
  for (int i = blockIdx.x * blockDim.x + threadIdx.x; i < n4; i += gridDim.x * blockDim.x) {
    fl4 v = ((const fl4*)x)[i];
    u16x4 h;
#pragma unroll
    for (int j = 0; j < 4; j++) h[j] = f2bf(v[j]);
    ((u16x4*)hi)[i] = h;
  }
}

// ---------------------------------------------------------------- transpose + cvt W[R][C] -> T[C][R] bf16
__global__ __launch_bounds__(256) void cvt_transpose(const float* __restrict__ W,
                                                     unsigned short* __restrict__ T,
                                                     int R, int C) {
  __shared__ float tile[32][33];
  const int c0 = blockIdx.x * 32, r0 = blockIdx.y * 32;
  const int tx = threadIdx.x, ty = threadIdx.y;  // (32,8)
#pragma unroll
  for (int i = 0; i < 4; i++) tile[ty + 8 * i][tx] = W[(size_t)(r0 + ty + 8 * i) * C + c0 + tx];
  __syncthreads();
#pragma unroll
  for (int i = 0; i < 4; i++) {
    const float v = tile[tx][ty + 8 * i];
    T[(size_t)(c0 + ty + 8 * i) * R + r0 + tx] = f2bf(v);
  }
}

// ---------------------------------------------------------------- ring-pipelined GEMM (proven r7)
template <bool OUT_BF16>
__global__ __launch_bounds__(512, 1) void gemm_ring(const unsigned short* __restrict__ A,
                                                    const unsigned short* __restrict__ Bt,
                                                    const float* __restrict__ bias,
                                                    void* __restrict__ Cout, int Ndim) {
  constexpr int KDIM  = 2048;
  constexpr int NT    = KDIM / 64;
  constexpr int ASLOT = 256 * 64;
  constexpr int BSLOT = 128 * 64;
  constexpr int SLOT  = ASLOT + BSLOT;
  __shared__ __align__(16) unsigned short smem[3 * SLOT];  // 144 KB

  const int tid = threadIdx.x;
  const int wid = tid >> 6, lane = tid & 63;
  const int wm = wid >> 2, wn = wid & 3;
  const int g = lane >> 4, q = lane & 15;
  const int n0 = blockIdx.x * 128, m0 = blockIdx.y * 256;

  const int srow = (wid << 3) + (lane >> 3);
  const int scol = (((lane & 7) ^ (lane >> 3)) << 4);
  const char* gA = (const char*)A  + ((size_t)(m0 + srow) * KDIM) * 2 + scol;
  const char* gB = (const char*)Bt + ((size_t)(n0 + srow) * KDIM) * 2 + scol;
  const int dbase = ((wid << 3)) << 7;

  f32x4 acc[8][2] = {};
  const int axor = (q & 7) << 4;

  auto STAGE = [&](int tt, int slot) {
    char* sA = (char*)(smem + slot * SLOT);
    char* sB = (char*)(smem + slot * SLOT + ASLOT);
    const size_t koff = (size_t)tt << 7;
#pragma unroll
    for (int i = 0; i < 4; i++)
      async_cp16(gA + (size_t)(i * 64) * (KDIM * 2) + koff, sA + dbase + (i << 13));
#pragma unroll
    for (int i = 0; i < 2; i++)
      async_cp16(gB + (size_t)(i * 64) * (KDIM * 2) + koff, sB + dbase + (i << 13));
  };

  auto COMPUTE = [&](int slot) {
    const char* sA = (const char*)(smem + slot * SLOT);
    const char* sB = (const char*)(smem + slot * SLOT + ASLOT);
#pragma unroll
    for (int ks = 0; ks < 2; ks++) {
      const int kb = (ks << 6) + (g << 4);
      bf16x8 av[8], bv[2];
#pragma unroll
      for (int nf = 0; nf < 2; nf++) {
        const int row = (wn << 5) + (nf << 4) + q;
        bv[nf] = *(const bf16x8*)(sB + (row << 7) + (kb ^ axor));
      }
#pragma unroll
      for (int mf = 0; mf < 8; mf++) {
        const int row = (wm << 7) + (mf << 4) + q;
        av[mf] = *(const bf16x8*)(sA + (row << 7) + (kb ^ axor));
      }
#pragma unroll
      for (int mf = 0; mf < 8; mf++)
#pragma unroll
        for (int nf = 0; nf < 2; nf++)
          acc[mf][nf] = mfma_bf16(av[mf], bv[nf], acc[mf][nf]);
    }
  };

  STAGE(0, 0);
  STAGE(1, 1);
  int s2 = 2, sc = 0;
#pragma unroll 1
  for (int t = 0; t < NT - 2; ++t) {
    asm volatile("s_waitcnt vmcnt(6)" ::: "memory");
    __builtin_amdgcn_s_barrier();
    asm volatile("" ::: "memory");
    STAGE(t + 2, s2);
    COMPUTE(sc);
    s2 = (s2 == 2) ? 0 : s2 + 1;
    sc = (sc == 2) ? 0 : sc + 1;
  }
  asm volatile("s_waitcnt vmcnt(6)" ::: "memory");
  __builtin_amdgcn_s_barrier();
  asm volatile("" ::: "memory");
  COMPUTE(sc);
  sc = (sc == 2) ? 0 : sc + 1;
  asm volatile("s_waitcnt vmcnt(0)" ::: "memory");
  __builtin_amdgcn_s_barrier();
  asm volatile("" ::: "memory");
  COMPUTE(sc);

  float bvv[2];
#pragma unroll
  for (int nf = 0; nf < 2; nf++) bvv[nf] = bias[n0 + (wn << 5) + (nf << 4) + q];
#pragma unroll
  for (int mf = 0; mf < 8; mf++) {
    const int rowg = m0 + (wm << 7) + (mf << 4) + (g << 2);
#pragma unroll
    for (int nf = 0; nf < 2; nf++) {
      const int colg = n0 + (wn << 5) + (nf << 4) + q;
#pragma unroll
      for (int r = 0; r < 4; r++) {
        const float v = acc[mf][nf][r] + bvv[nf];
        if (OUT_BF16)
          ((unsigned short*)Cout)[(size_t)(rowg + r) * Ndim + colg] = f2bf(v);
        else
          ((float*)Cout)[(size_t)(rowg + r) * Ndim + colg] = v;
      }
    }
  }
}

// ---------------------------------------------------------------- V slice of QKV -> V^T [z][d][s]
__global__ __launch_bounds__(256) void transpose_v(const unsigned short* __restrict__ qkv,
                                                   unsigned short* __restrict__ vt) {
  __shared__ __align__(16) unsigned short tile[64][136];
  const int z = blockIdx.y, b = z >> 4, h = z & 15;
  const int s0 = blockIdx.x << 6;
  const int t = threadIdx.x;
#pragma unroll
  for (int i = 0; i < 4; i++) {
    const int idx = t + (i << 8);
    const int row = idx >> 4, ch = idx & 15;
    *(s16x8*)&tile[row][ch << 3] =
        *(const s16x8*)(qkv + (size_t)(b * SEQ + s0 + row) * N3 + 2 * HID + h * HDIM + (ch << 3));
  }
  __syncthreads();
#pragma unroll
  for (int i = 0; i < 4; i++) {
    const int idx = t + (i << 8);
    const int d = idx >> 3, sc = idx & 7;
    s16x8 v;
#pragma unroll
    for (int j = 0; j < 8; j++) v[j] = (short)tile[(sc << 3) + j][d];
    *(s16x8*)(vt + (size_t)(z * HDIM + d) * SEQ + s0 + (sc << 3)) = v;
  }
}

// ---------------------------------------------------------------- flash attention v2:
// 32x32 MFMA, swapped QK^T (lane = one q-row), in-register softmax + P via
// cvt_pk_bf16 + permlane32_swap (T12) -- no P LDS, no per-tile lgkm fence wall.
// 3-slot K/V ring + counted vmcnt (T3/T4), T1 XCD swizzle, defer-max (T13).
__global__ __launch_bounds__(512, 2) void attn_kernel(const unsigned short* __restrict__ qkv,
                                                      const unsigned short* __restrict__ vt,
                                                      const float* __restrict__ mask,
                                                      unsigned short* __restrict__ ctx) {
  constexpr int NT    = SEQ / 64;
  constexpr int KSLOT = 64 * 128;           // shorts (16 KB)
  constexpr int VSLOT = 128 * 64;
  constexpr int SLOT  = KSLOT + VSLOT;      // 32 KB
  __shared__ __align__(16) unsigned short sKV[3 * SLOT];   // 96 KB
  __shared__ __align__(16) float sM[SEQ];                  // 8 KB: mask * LOG2E

  const int bid = blockIdx.x;
  const int z  = ((bid & 7) << 2) + ((bid >> 3) >> 3);
  const int qb = (bid >> 3) & 7;
  const int b = z >> 4, h = z & 15;
  const int tid = threadIdx.x, wid = tid >> 6, lane = tid & 63;
  const int l31 = lane & 31, hi = lane >> 5;
  const int q0w = (qb << 8) + (wid << 5);   // 256 q-rows/block, 32/wave

  // mask -> LDS (x LOG2E), once
  {
    fl4 m = ((const fl4*)(mask + (size_t)b * SEQ))[tid];
    m *= LOG2E;
    ((fl4*)sM)[tid] = m;
  }

  // Q B-frags: lane supplies Q[q=l31][d = 16*kc + 8*hi + j]
  bf16x8 bq[8];
  {
    const char* qrow = (const char*)(qkv + (size_t)(b * SEQ + q0w + l31) * N3 + h * HDIM);
#pragma unroll
    for (int kc = 0; kc < 8; kc++) bq[kc] = *(const bf16x8*)(qrow + (kc << 5) + (hi << 4));
  }

  f32x16 acc2[4] = {};       // ctx[q'=crow(r,hi)][d = 32*db + l31]
  float mrun = -1e30f, lrun = 0.f;

  const char* gK = (const char*)qkv + ((size_t)(b * SEQ) * N3 + HID + h * HDIM) * 2;
  const char* gV = (const char*)vt + ((size_t)z * HDIM * SEQ) * 2;

  auto STAGE = [&](int tt, int slot) {
    char* base = (char*)(sKV + slot * SLOT);
    const int k0 = tt << 6;
#pragma unroll
    for (int i = 0; i < 2; i++) {
      const int krow = (i << 5) + (tid >> 4);
      const int kc = (((tid & 15) << 4)) ^ ((krow & 7) << 4);
      async_cp16(gK + ((size_t)(k0 + krow) * N3) * 2 + kc, base + (i << 13) + (wid << 10));
    }
#pragma unroll
    for (int i = 0; i < 2; i++) {
      const int vrow = (i << 6) + (tid >> 3);
      const int vc = (((tid & 7) << 4)) ^ ((vrow & 7) << 4);
      async_cp16(gV + ((size_t)vrow * SEQ + k0) * 2 + vc,
                 base + (KSLOT * 2) + (i << 13) + (wid << 10));
    }
  };

  auto COMPUTE = [&](int t, int slot) {
    const char* sK = (const char*)(sKV + slot * SLOT);
    const char* sV = (const char*)(sKV + slot * SLOT + KSLOT);
    const int k0 = t << 6;

    // QK^T swapped: C[key = 32*kb + crow(r,hi)][q = l31]
    f32x16 accs[2] = {};
    __builtin_amdgcn_s_setprio(1);
#pragma unroll
    for (int kb = 0; kb < 2; kb++)
#pragma unroll
      for (int kc = 0; kc < 8; kc++) {
        const bf16x8 ka = *(const bf16x8*)(sK + (((kb << 5) + l31) << 8) +
                                           (((kc << 5) + (hi << 4)) ^ ((l31 & 7) << 4)));
        accs[kb] = mfma32(ka, bq[kc], accs[kb]);
      }
    __builtin_amdgcn_s_setprio(0);

    // scores (log2 domain): p_[kb][r] first holds s, then exp2(s - mrun)
    float p_[2][16];
#pragma unroll
    for (int kb = 0; kb < 2; kb++) {
      fl4 mk[4];
#pragma unroll
      for (int m = 0; m < 4; m++) mk[m] = *(const fl4*)&sM[k0 + (kb << 5) + (m << 3) + (hi << 2)];
#pragma unroll
      for (int r = 0; r < 16; r++)
        p_[kb][r] = fmaf(accs[kb][r], SCALE_LOG2E, mk[r >> 2][r & 3]);
    }
    float mt = p_[0][0];
#pragma unroll
    for (int kb = 0; kb < 2; kb++)
#pragma unroll
      for (int r = 0; r < 16; r++) mt = fmaxf(mt, p_[kb][r]);
    mt = fmaxf(mt, __shfl_xor(mt, 32));
    if (!__all(mt <= mrun + DEFER_THR)) {   // defer-max (T13)
      const float mnew = fmaxf(mrun, mt);
      const float fs = exp2f(mrun - mnew);
      lrun *= fs;
#pragma unroll
      for (int r = 0; r < 16; r++) {
        const int qr = (r & 3) + ((r >> 2) << 3) + (hi << 2);
        const float fr = __shfl(fs, (lane & 32) | qr);
#pragma unroll
        for (int db = 0; db < 4; db++) acc2[db][r] *= fr;
      }
      mrun = mnew;
    }
    float ps = 0.f;
#pragma unroll
    for (int kb = 0; kb < 2; kb++)
#pragma unroll
      for (int r = 0; r < 16; r++) {
        const float e = exp2f(p_[kb][r] - mrun);
        p_[kb][r] = e;
        ps += e;
      }
    ps += __shfl_xor(ps, 32);
    lrun += ps;

    // P -> bf16 A-frags in registers (T12): pa[ks] covers keys [16*ks, 16*ks+16)
    bf16x8 pa[4];
#pragma unroll
    for (int kb = 0; kb < 2; kb++)
#pragma unroll
      for (int hh = 0; hh < 2; hh++) {
        const float* pp = &p_[kb][hh << 3];
        const unsigned x01 = cvt_pk_bf16(pp[0], pp[1]);
        const unsigned x23 = cvt_pk_bf16(pp[2], pp[3]);
        const unsigned y01 = cvt_pk_bf16(pp[4], pp[5]);
        const unsigned y23 = cvt_pk_bf16(pp[6], pp[7]);
        const u32x2 sa = __builtin_amdgcn_permlane32_swap(x01, y01, false, false);
        const u32x2 sb = __builtin_amdgcn_permlane32_swap(x23, y23, false, false);
        const u32x4 w = {sa[0], sb[0], sa[1], sb[1]};
        pa[(kb << 1) + hh] = __builtin_bit_cast(bf16x8, w);
      }

    // PV: ctx[q'][d] += P[q'][key] * V[key][d];  B-frag from sV[d][key]
    __builtin_amdgcn_s_setprio(1);
#pragma unroll
    for (int db = 0; db < 4; db++)
#pragma unroll
      for (int ks = 0; ks < 4; ks++) {
        const bf16x8 bv = *(const bf16x8*)(sV + (((db << 5) + l31) << 7) +
                                           (((ks << 5) + (hi << 4)) ^ ((l31 & 7) << 4)));
        acc2[db] = mfma32(pa[ks], bv, acc2[db]);
      }
    __builtin_amdgcn_s_setprio(0);
  };

  STAGE(0, 0);
  STAGE(1, 1);
  __syncthreads();       // sM visible; prologue drain only
  int s2 = 2, sc = 0;
#pragma unroll 1
  for (int t = 0; t < NT - 2; ++t) {
    asm volatile("s_waitcnt vmcnt(4)" ::: "memory");
    __builtin_amdgcn_s_barrier();
    asm volatile("" ::: "memory");
    STAGE(t + 2, s2);
    COMPUTE(t, sc);
    s2 = (s2 == 2) ? 0 : s2 + 1;
    sc = (sc == 2) ? 0 : sc + 1;
  }
  asm volatile("s_waitcnt vmcnt(4)" ::: "memory");
  __builtin_amdgcn_s_barrier();
  asm volatile("" ::: "memory");
  COMPUTE(NT - 2, sc);
  sc = (sc == 2) ? 0 : sc + 1;
  asm volatile("s_waitcnt vmcnt(0)" ::: "memory");
  __builtin_amdgcn_s_barrier();
  asm volatile("" ::: "memory");
  COMPUTE(NT - 1, sc);

  // epilogue: normalize + write (row q' = crow(r,hi), col d = 32*db + l31)
  const float inv = 1.f / lrun;
#pragma unroll
  for (int r = 0; r < 16; r++) {
    const int qr = (r & 3) + ((r >> 2) << 3) + (hi << 2);
    const float fr = __shfl(inv, (lane & 32) | qr);
    unsigned short* crow = ctx + (size_t)(b * SEQ + q0w + qr) * HID + h * HDIM + l31;
#pragma unroll
    for (int db = 0; db < 4; db++) crow[db << 5] = f2bf(acc2[db][r] * fr);
  }
}

// ---------------------------------------------------------------- launch
extern "C" void kernel_launch(void* const* d_in, const int* in_sizes, int n_in,
                              void* d_out, int out_size, void* d_ws, size_t ws_size,
                              hipStream_t stream) {
  const float* hs   = (const float*)d_in[0];
  const float* mask = (const float*)d_in[1];
  const float* Wqkv = (const float*)d_in[2];
  const float* bqkv = (const float*)d_in[3];
  const float* Wout = (const float*)d_in[4];
  const float* bout = (const float*)d_in[5];

  char* ws = (char*)d_ws;
  size_t off = 0;
  auto alloc = [&](size_t n) { char* p = ws + off; off += (n + 255) & ~(size_t)255; return p; };
  unsigned short* hs_bf = (unsigned short*)alloc((size_t)MROWS * HID * 2);
  unsigned short* wq_bf = (unsigned short*)alloc((size_t)N3 * HID * 2);
  unsigned short* wo_bf = (unsigned short*)alloc((size_t)HID * HID * 2);
  unsigned short* qkvb  = (unsigned short*)alloc((size_t)MROWS * N3 * 2);
  unsigned short* vtb   = (unsigned short*)alloc((size_t)BATCH * NHEAD * HDIM * SEQ * 2);
  unsigned short* ctxb  = (unsigned short*)alloc((size_t)MROWS * HID * 2);
  (void)ws_size;

  cvt_bf16<<<2048, 256, 0, stream>>>(hs, hs_bf, MROWS * HID / 4);
  dim3 tb(32, 8);
  cvt_transpose<<<dim3(N3 / 32, HID / 32), tb, 0, stream>>>(Wqkv, wq_bf, HID, N3);
  cvt_transpose<<<dim3(HID / 32, HID / 32), tb, 0, stream>>>(Wout, wo_bf, HID, HID);
  gemm_ring<true ><<<dim3(N3 / 128, MROWS / 256), 512, 0, stream>>>(hs_bf, wq_bf, bqkv, qkvb, N3);
  transpose_v<<<dim3(SEQ / 64, BATCH * NHEAD), 256, 0, stream>>>(qkvb, vtb);
  attn_kernel<<<256, 512, 0, stream>>>(qkvb, vtb, mask, ctxb);
  gemm_ring<false><<<dim3(HID / 128, MROWS / 256), 512, 0, stream>>>(ctxb, wo_bf, bout, (float*)d_out, HID);
}

// Round 11
// 267.126 us; speedup vs baseline: 1.8136x; 1.0066x over previous
//
#include <hip/hip_runtime.h>
#include <hip/hip_bf16.h>
#include <stdint.h>

typedef __attribute__((ext_vector_type(4)))  float   f32x4;
typedef __attribute__((ext_vector_type(16))) float   f32x16;
typedef __attribute__((ext_vector_type(8)))  __bf16  bf16x8;
typedef __attribute__((ext_vector_type(8)))  short   s16x8;
typedef __attribute__((ext_vector_type(4)))  unsigned short u16x4;
typedef __attribute__((ext_vector_type(4)))  float   fl4;
typedef __attribute__((ext_vector_type(2)))  unsigned int u32x2;
typedef __attribute__((ext_vector_type(4)))  unsigned int u32x4;

#define DEVFN static __device__ __forceinline__

constexpr int BATCH = 2, SEQ = 2048, HID = 2048, NHEAD = 16, HDIM = 128;
constexpr int MROWS = BATCH * SEQ;   // 4096
constexpr int N3    = 3 * HID;       // 6144
constexpr float LOG2E = 1.44269504088896340736f;
constexpr float SCALE_LOG2E = 0.12751649736170852f;   // (1/sqrt(128)) * log2(e)
constexpr float DEFER_THR = 11.541560327111708f;      // 8 * log2(e)

DEVFN unsigned short f2bf(float f) {  // RNE float->bf16
  unsigned int u = __float_as_uint(f);
  u += 0x7FFFu + ((u >> 16) & 1u);
  return (unsigned short)(u >> 16);
}

DEVFN void async_cp16(const void* g, void* l) {
  __builtin_amdgcn_global_load_lds(
      (__attribute__((address_space(1))) void*)g,
      (__attribute__((address_space(3))) void*)l, 16, 0, 0);
}

DEVFN f32x4 mfma_bf16(bf16x8 a, bf16x8 b, f32x4 c) {
  return __builtin_amdgcn_mfma_f32_16x16x32_bf16(a, b, c, 0, 0, 0);
}
DEVFN f32x16 mfma32(bf16x8 a, bf16x8 b, f32x16 c) {
  return __builtin_amdgcn_mfma_f32_32x32x16_bf16(a, b, c, 0, 0, 0);
}
DEVFN unsigned cvt_pk_bf16(float lo, float hi) {
  unsigned r;
  asm("v_cvt_pk_bf16_f32 %0, %1, %2" : "=v"(r) : "v"(lo), "v"(hi));
  return r;
}

// ---------------------------------------------------------------- fp32 -> bf16 (RNE)
__global__ __launch_bounds__(256) void cvt_bf16(const float* __restrict__ x,
                                                unsigned short* __restrict__ hi, int n4) {
  for (int i = blockIdx.x * blockDim.x + threadIdx.x; i < n4; i += gridDim.x * blockDim.x) {
    fl4 v = ((const fl4*)x)[i];
    u16x4 h;
#pragma unroll
    for (int j = 0; j < 4; j++) h[j] = f2bf(v[j]);
    ((u16x4*)hi)[i] = h;
  }
}

// ---------------------------------------------------------------- transpose + cvt W[R][C] -> T[C][R] bf16
__global__ __launch_bounds__(256) void cvt_transpose(const float* __restrict__ W,
                                                     unsigned short* __restrict__ T,
                                                     int R, int C) {
  __shared__ float tile[32][33];
  const int c0 = blockIdx.x * 32, r0 = blockIdx.y * 32;
  const int tx = threadIdx.x, ty = threadIdx.y;  // (32,8)
#pragma unroll
  for (int i = 0; i < 4; i++) tile[ty + 8 * i][tx] = W[(size_t)(r0 + ty + 8 * i) * C + c0 + tx];
  __syncthreads();
#pragma unroll
  for (int i = 0; i < 4; i++) {
    const float v = tile[tx][ty + 8 * i];
    T[(size_t)(c0 + ty + 8 * i) * R + r0 + tx] = f2bf(v);
  }
}

// ---------------------------------------------------------------- ring-pipelined GEMM (proven r7)
template <bool OUT_BF16>
__global__ __launch_bounds__(512, 1) void gemm_ring(const unsigned short* __restrict__ A,
                                                    const unsigned short* __restrict__ Bt,
                                                    const float* __restrict__ bias,
                                                    void* __restrict__ Cout, int Ndim) {
  constexpr int KDIM  = 2048;
  constexpr int NT    = KDIM / 64;
  constexpr int ASLOT = 256 * 64;
  constexpr int BSLOT = 128 * 64;
  constexpr int SLOT  = ASLOT + BSLOT;
  __shared__ __align__(16) unsigned short smem[3 * SLOT];  // 144 KB

  const int tid = threadIdx.x;
  const int wid = tid >> 6, lane = tid & 63;
  const int wm = wid >> 2, wn = wid & 3;
  const int g = lane >> 4, q = lane & 15;
  const int n0 = blockIdx.x * 128, m0 = blockIdx.y * 256;

  const int srow = (wid << 3) + (lane >> 3);
  const int scol = (((lane & 7) ^ (lane >> 3)) << 4);
  const char* gA = (const char*)A  + ((size_t)(m0 + srow) * KDIM) * 2 + scol;
  const char* gB = (const char*)Bt + ((size_t)(n0 + srow) * KDIM) * 2 + scol;
  const int dbase = ((wid << 3)) << 7;

  f32x4 acc[8][2] = {};
  const int axor = (q & 7) << 4;

  auto STAGE = [&](int tt, int slot) {
    char* sA = (char*)(smem + slot * SLOT);
    char* sB = (char*)(smem + slot * SLOT + ASLOT);
    const size_t koff = (size_t)tt << 7;
#pragma unroll
    for (int i = 0; i < 4; i++)
      async_cp16(gA + (size_t)(i * 64) * (KDIM * 2) + koff, sA + dbase + (i << 13));
#pragma unroll
    for (int i = 0; i < 2; i++)
      async_cp16(gB + (size_t)(i * 64) * (KDIM * 2) + koff, sB + dbase + (i << 13));
  };

  auto COMPUTE = [&](int slot) {
    const char* sA = (const char*)(smem + slot * SLOT);
    const char* sB = (const char*)(smem + slot * SLOT + ASLOT);
#pragma unroll
    for (int ks = 0; ks < 2; ks++) {
      const int kb = (ks << 6) + (g << 4);
      bf16x8 av[8], bv[2];
#pragma unroll
      for (int nf = 0; nf < 2; nf++) {
        const int row = (wn << 5) + (nf << 4) + q;
        bv[nf] = *(const bf16x8*)(sB + (row << 7) + (kb ^ axor));
      }
#pragma unroll
      for (int mf = 0; mf < 8; mf++) {
        const int row = (wm << 7) + (mf << 4) + q;
        av[mf] = *(const bf16x8*)(sA + (row << 7) + (kb ^ axor));
      }
#pragma unroll
      for (int mf = 0; mf < 8; mf++)
#pragma unroll
        for (int nf = 0; nf < 2; nf++)
          acc[mf][nf] = mfma_bf16(av[mf], bv[nf], acc[mf][nf]);
    }
  };

  STAGE(0, 0);
  STAGE(1, 1);
  int s2 = 2, sc = 0;
#pragma unroll 1
  for (int t = 0; t < NT - 2; ++t) {
    asm volatile("s_waitcnt vmcnt(6)" ::: "memory");
    __builtin_amdgcn_s_barrier();
    asm volatile("" ::: "memory");
    STAGE(t + 2, s2);
    COMPUTE(sc);
    s2 = (s2 == 2) ? 0 : s2 + 1;
    sc = (sc == 2) ? 0 : sc + 1;
  }
  asm volatile("s_waitcnt vmcnt(6)" ::: "memory");
  __builtin_amdgcn_s_barrier();
  asm volatile("" ::: "memory");
  COMPUTE(sc);
  sc = (sc == 2) ? 0 : sc + 1;
  asm volatile("s_waitcnt vmcnt(0)" ::: "memory");
  __builtin_amdgcn_s_barrier();
  asm volatile("" ::: "memory");
  COMPUTE(sc);

  float bvv[2];
#pragma unroll
  for (int nf = 0; nf < 2; nf++) bvv[nf] = bias[n0 + (wn << 5) + (nf << 4) + q];
#pragma unroll
  for (int mf = 0; mf < 8; mf++) {
    const int rowg = m0 + (wm << 7) + (mf << 4) + (g << 2);
#pragma unroll
    for (int nf = 0; nf < 2; nf++) {
      const int colg = n0 + (wn << 5) + (nf << 4) + q;
#pragma unroll
      for (int r = 0; r < 4; r++) {
        const float v = acc[mf][nf][r] + bvv[nf];
        if (OUT_BF16)
          ((unsigned short*)Cout)[(size_t)(rowg + r) * Ndim + colg] = f2bf(v);
        else
          ((float*)Cout)[(size_t)(rowg + r) * Ndim + colg] = v;
      }
    }
  }
}

// ---------------------------------------------------------------- V slice of QKV -> V^T [z][d][s]
__global__ __launch_bounds__(256) void transpose_v(const unsigned short* __restrict__ qkv,
                                                   unsigned short* __restrict__ vt) {
  __shared__ __align__(16) unsigned short tile[64][136];
  const int z = blockIdx.y, b = z >> 4, h = z & 15;
  const int s0 = blockIdx.x << 6;
  const int t = threadIdx.x;
#pragma unroll
  for (int i = 0; i < 4; i++) {
    const int idx = t + (i << 8);
    const int row = idx >> 4, ch = idx & 15;
    *(s16x8*)&tile[row][ch << 3] =
        *(const s16x8*)(qkv + (size_t)(b * SEQ + s0 + row) * N3 + 2 * HID + h * HDIM + (ch << 3));
  }
  __syncthreads();
#pragma unroll
  for (int i = 0; i < 4; i++) {
    const int idx = t + (i << 8);
    const int d = idx >> 3, sc = idx & 7;
    s16x8 v;
#pragma unroll
    for (int j = 0; j < 8; j++) v[j] = (short)tile[(sc << 3) + j][d];
    *(s16x8*)(vt + (size_t)(z * HDIM + d) * SEQ + s0 + (sc << 3)) = v;
  }
}

// ---------------------------------------------------------------- flash attention v3:
// 4 waves x 32 q-rows, 512 blocks -> 2 barrier-independent blocks/CU (phase
// decorrelation). Ring-2 K/V (72 KB/block), loads fly during COMPUTE, drain after.
// 4-bit XOR swizzles: K rows 256B; V packed [dd=d&63][dhi*8+kc] 256B rows.
// In-register softmax (T12), defer-max (T13), setprio (T5), T1 XCD swizzle.
__global__ __launch_bounds__(256, 2) void attn_kernel(const unsigned short* __restrict__ qkv,
                                                      const unsigned short* __restrict__ vt,
                                                      const float* __restrict__ mask,
                                                      unsigned short* __restrict__ ctx) {
  constexpr int NT    = SEQ / 64;
  constexpr int KSLOT = 64 * 128;           // shorts (16 KB)
  constexpr int VSLOT = 64 * 128;           // shorts (16 KB), packed 64 x 256B rows
  constexpr int SLOT  = KSLOT + VSLOT;      // 32 KB
  __shared__ __align__(16) unsigned short sKV[2 * SLOT];   // 64 KB
  __shared__ __align__(16) float sM[SEQ];                  // 8 KB: mask * LOG2E

  // T1: xcd = bid&7 hosts 4 z-values (4 MB K/V -> one L2)
  const int bid = blockIdx.x;
  const int idx = bid >> 3;
  const int z  = ((bid & 7) << 2) + (idx >> 4);
  const int qb = idx & 15;
  const int b = z >> 4, h = z & 15;
  const int tid = threadIdx.x, wid = tid >> 6, lane = tid & 63;
  const int l31 = lane & 31, hi = lane >> 5;
  const int q0w = (qb << 7) + (wid << 5);   // 128 q-rows/block, 32/wave

  // mask -> LDS (x LOG2E), once: 256 thr x fl4 x 2
#pragma unroll
  for (int j = 0; j < 2; j++) {
    fl4 m = ((const fl4*)(mask + (size_t)b * SEQ))[tid + (j << 8)];
    m *= LOG2E;
    ((fl4*)sM)[tid + (j << 8)] = m;
  }

  // Q B-frags: lane supplies Q[q=l31][d = 16*kc + 8*hi + j]
  bf16x8 bq[8];
  {
    const char* qrow = (const char*)(qkv + (size_t)(b * SEQ + q0w + l31) * N3 + h * HDIM);
#pragma unroll
    for (int kc = 0; kc < 8; kc++) bq[kc] = *(const bf16x8*)(qrow + (kc << 5) + (hi << 4));
  }

  f32x16 acc2[4] = {};       // ctx[q'=crow(r,hi)][d = 32*db + l31]
  float mrun = -1e30f, lrun = 0.f;

  const char* gK = (const char*)qkv + ((size_t)(b * SEQ) * N3 + HID + h * HDIM) * 2;
  const char* gV = (const char*)vt + ((size_t)z * HDIM * SEQ) * 2;

  // Stage one 64-key tile (K 16KB + V 16KB) with 256 threads: 4+4 cp16/thread.
  // Dest linear (wave-uniform base + lane*16); source pre-inverse-swizzled.
  auto STAGE = [&](int tt, int slot) {
    char* kb_ = (char*)(sKV + slot * SLOT);
    char* vb_ = kb_ + KSLOT * 2;
    const int k0 = tt << 6;
#pragma unroll
    for (int i = 0; i < 4; i++) {
      const int row = (i << 4) + (wid << 2) + (lane >> 4);   // 0..63 (krow / dd)
      const int sl  = lane & 15;
      const int dst = (i << 12) + (wid << 10);
      // K row = key, 256B; slot sl holds src slot sl^(row&15)
      async_cp16(gK + ((size_t)(k0 + row) * N3) * 2 + (((sl ^ (row & 15))) << 4),
                 kb_ + dst);
      // V packed: row dd, slot s holds logical s' = s^(dd&15); s' = dhi*8 + kc
      const int sv  = sl ^ (row & 15);
      const int dhi = sv >> 3, kc8 = sv & 7;
      async_cp16(gV + ((size_t)((dhi << 6) + row) * SEQ + k0 + (kc8 << 3)) * 2,
                 vb_ + dst);
    }
  };

  auto COMPUTE = [&](int t, int slot) {
    const char* sK = (const char*)(sKV + slot * SLOT);
    const char* sV = (const char*)(sKV + slot * SLOT + KSLOT);
    const int k0 = t << 6;

    // QK^T swapped: C[key = 32*kb + crow(r,hi)][q = l31]
    f32x16 accs[2] = {};
    __builtin_amdgcn_s_setprio(1);
#pragma unroll
    for (int kb = 0; kb < 2; kb++)
#pragma unroll
      for (int kc = 0; kc < 8; kc++) {
        const int key = (kb << 5) + l31;
        const bf16x8 ka = *(const bf16x8*)(sK + (key << 8) +
                                           ((((kc << 1) + hi) ^ (l31 & 15)) << 4));
        accs[kb] = mfma32(ka, bq[kc], accs[kb]);
      }
    __builtin_amdgcn_s_setprio(0);

    // scores (log2 domain)
    float p_[2][16];
#pragma unroll
    for (int kb = 0; kb < 2; kb++) {
      fl4 mk[4];
#pragma unroll
      for (int m = 0; m < 4; m++) mk[m] = *(const fl4*)&sM[k0 + (kb << 5) + (m << 3) + (hi << 2)];
#pragma unroll
      for (int r = 0; r < 16; r++)
        p_[kb][r] = fmaf(accs[kb][r], SCALE_LOG2E, mk[r >> 2][r & 3]);
    }
    float mt = p_[0][0];
#pragma unroll
    for (int kb = 0; kb < 2; kb++)
#pragma unroll
      for (int r = 0; r < 16; r++) mt = fmaxf(mt, p_[kb][r]);
    mt = fmaxf(mt, __shfl_xor(mt, 32));
    if (!__all(mt <= mrun + DEFER_THR)) {   // defer-max (T13)
      const float mnew = fmaxf(mrun, mt);
      const float fs = exp2f(mrun - mnew);
      lrun *= fs;
#pragma unroll
      for (int r = 0; r < 16; r++) {
        const int qr = (r & 3) + ((r >> 2) << 3) + (hi << 2);
        const float fr = __shfl(fs, (lane & 32) | qr);
#pragma unroll
        for (int db = 0; db < 4; db++) acc2[db][r] *= fr;
      }
      mrun = mnew;
    }
    float ps = 0.f;
#pragma unroll
    for (int kb = 0; kb < 2; kb++)
#pragma unroll
      for (int r = 0; r < 16; r++) {
        const float e = exp2f(p_[kb][r] - mrun);
        p_[kb][r] = e;
        ps += e;
      }
    ps += __shfl_xor(ps, 32);
    lrun += ps;

    // P -> bf16 A-frags in registers (T12)
    bf16x8 pa[4];
#pragma unroll
    for (int kb = 0; kb < 2; kb++)
#pragma unroll
      for (int hh = 0; hh < 2; hh++) {
        const float* pp = &p_[kb][hh << 3];
        const unsigned x01 = cvt_pk_bf16(pp[0], pp[1]);
        const unsigned x23 = cvt_pk_bf16(pp[2], pp[3]);
        const unsigned y01 = cvt_pk_bf16(pp[4], pp[5]);
        const unsigned y23 = cvt_pk_bf16(pp[6], pp[7]);
        const u32x2 sa = __builtin_amdgcn_permlane32_swap(x01, y01, false, false);
        const u32x2 sb = __builtin_amdgcn_permlane32_swap(x23, y23, false, false);
        const u32x4 w = {sa[0], sb[0], sa[1], sb[1]};
        pa[(kb << 1) + hh] = __builtin_bit_cast(bf16x8, w);
      }

    // PV: B-frag from packed sV: row dd = (db&1)*32+l31, slot = (db>>1)*8+ks*2+hi
    __builtin_amdgcn_s_setprio(1);
#pragma unroll
    for (int db = 0; db < 4; db++) {
      const int dd = ((db & 1) << 5) + l31;
#pragma unroll
      for (int ks = 0; ks < 4; ks++) {
        const int sv = ((db >> 1) << 3) + (ks << 1) + hi;
        const bf16x8 bv = *(const bf16x8*)(sV + (dd << 8) + ((sv ^ (l31 & 15)) << 4));
        acc2[db] = mfma32(pa[ks], bv, acc2[db]);
      }
    }
    __builtin_amdgcn_s_setprio(0);
  };

  // Ring-2: STAGE(t+1) flies during COMPUTE(t); drain + barrier after.
  STAGE(0, 0);
  __syncthreads();   // drains cp16 (full waitcnt) + sM visible
#pragma unroll 1
  for (int t = 0; t < NT - 1; ++t) {
    STAGE(t + 1, (t + 1) & 1);
    COMPUTE(t, t & 1);
    asm volatile("s_waitcnt vmcnt(0)" ::: "memory");
    __builtin_amdgcn_s_barrier();
    asm volatile("" ::: "memory");
  }
  COMPUTE(NT - 1, (NT - 1) & 1);

  // epilogue: normalize + write (row q' = crow(r,hi), col d = 32*db + l31)
  const float inv = 1.f / lrun;
#pragma unroll
  for (int r = 0; r < 16; r++) {
    const int qr = (r & 3) + ((r >> 2) << 3) + (hi << 2);
    const float fr = __shfl(inv, (lane & 32) | qr);
    unsigned short* crow = ctx + (size_t)(b * SEQ + q0w + qr) * HID + h * HDIM + l31;
#pragma unroll
    for (int db = 0; db < 4; db++) crow[db << 5] = f2bf(acc2[db][r] * fr);
  }
}

// ---------------------------------------------------------------- launch
extern "C" void kernel_launch(void* const* d_in, const int* in_sizes, int n_in,
                              void* d_out, int out_size, void* d_ws, size_t ws_size,
                              hipStream_t stream) {
  const float* hs   = (const float*)d_in[0];
  const float* mask = (const float*)d_in[1];
  const float* Wqkv = (const float*)d_in[2];
  const float* bqkv = (const float*)d_in[3];
  const float* Wout = (const float*)d_in[4];
  const float* bout = (const float*)d_in[5];

  char* ws = (char*)d_ws;
  size_t off = 0;
  auto alloc = [&](size_t n) { char* p = ws + off; off += (n + 255) & ~(size_t)255; return p; };
  unsigned short* hs_bf = (unsigned short*)alloc((size_t)MROWS * HID * 2);
  unsigned short* wq_bf = (unsigned short*)alloc((size_t)N3 * HID * 2);
  unsigned short* wo_bf = (unsigned short*)alloc((size_t)HID * HID * 2);
  unsigned short* qkvb  = (unsigned short*)alloc((size_t)MROWS * N3 * 2);
  unsigned short* vtb   = (unsigned short*)alloc((size_t)BATCH * NHEAD * HDIM * SEQ * 2);
  unsigned short* ctxb  = (unsigned short*)alloc((size_t)MROWS * HID * 2);
  (void)ws_size;

  cvt_bf16<<<2048, 256, 0, stream>>>(hs, hs_bf, MROWS * HID / 4);
  dim3 tb(32, 8);
  cvt_transpose<<<dim3(N3 / 32, HID / 32), tb, 0, stream>>>(Wqkv, wq_bf, HID, N3);
  cvt_transpose<<<dim3(HID / 32, HID / 32), tb, 0, stream>>>(Wout, wo_bf, HID, HID);
  gemm_ring<true ><<<dim3(N3 / 128, MROWS / 256), 512, 0, stream>>>(hs_bf, wq_bf, bqkv, qkvb, N3);
  transpose_v<<<dim3(SEQ / 64, BATCH * NHEAD), 256, 0, stream>>>(qkvb, vtb);
  attn_kernel<<<512, 256, 0, stream>>>(qkvb, vtb, mask, ctxb);
  gemm_ring<false><<<dim3(HID / 128, MROWS / 256), 512, 0, stream>>>(ctxb, wo_bf, bout, (float*)d_out, HID);
}